// Round 4
// baseline (910.516 us; speedup 1.0000x reference)
//
#include <hip/hip_runtime.h>
#include <math.h>

#define TIN   32
#define THID  32
#define TOUT  32
#define TEDGE 8

typedef __attribute__((ext_vector_type(8))) short bf16x8;
typedef __attribute__((ext_vector_type(4))) float f32x4;

#define MFMA16(a, b, c) __builtin_amdgcn_mfma_f32_16x16x32_bf16((a), (b), (c), 0, 0, 0)

// hardware packed f32->bf16 (RNE), 1 instruction
__device__ __forceinline__ unsigned int cvtpk(float lo, float hi) {
    unsigned int r;
    asm("v_cvt_pk_bf16_f32 %0, %1, %2" : "=v"(r) : "v"(lo), "v"(hi));
    return r;
}

__device__ __forceinline__ float silu_f(float x) {
    float e = __expf(-x);
    return x * __builtin_amdgcn_rcpf(1.0f + e);
}

union U4F { unsigned int u[4]; bf16x8 v; };

__device__ __forceinline__ bf16x8 pack8bf(const float* f) {
    U4F t;
    t.u[0] = cvtpk(f[0], f[1]);
    t.u[1] = cvtpk(f[2], f[3]);
    t.u[2] = cvtpk(f[4], f[5]);
    t.u[3] = cvtpk(f[6], f[7]);
    return t.v;
}

// A-fragment of transposed weights, with optional bias folded at k==Kreal+biasSlot
__device__ __forceinline__ bf16x8 load_wT(const float* __restrict__ W, int kbase, int ch, int Kreal) {
    float f[8];
    #pragma unroll
    for (int e = 0; e < 8; ++e) {
        int k = kbase + e;
        f[e] = (k < Kreal) ? W[k * 32 + ch] : 0.0f;
    }
    return pack8bf(f);
}
// layer-1 variant: k==73 carries be1[ch] (B-side supplies 1.0 there)
__device__ __forceinline__ bf16x8 load_wT1(const float* __restrict__ W, const float* __restrict__ bias,
                                           int kbase, int ch) {
    float f[8];
    #pragma unroll
    for (int e = 0; e < 8; ++e) {
        int k = kbase + e;
        f[e] = (k < 73) ? W[k * 32 + ch] : ((k == 73) ? bias[ch] : 0.0f);
    }
    return pack8bf(f);
}

// ---------------- phase 1: histogram of dst ----------------
__global__ __launch_bounds__(256) void hist_kernel(
    const int* __restrict__ dst, int* __restrict__ hist, int E)
{
    int e = blockIdx.x * 256 + threadIdx.x;
    if (e < E) atomicAdd(&hist[dst[e]], 1);
}

// ---------------- phase 2: exclusive scan (single block), writes base AND cursor ----------------
__global__ __launch_bounds__(1024) void scan_hist(
    const int* __restrict__ hist, int* __restrict__ base, int* __restrict__ cursor, int N)
{
    __shared__ int partial[1024];
    int t = threadIdx.x;
    int chunk = (N + 1023) / 1024;
    int begin = t * chunk;
    int end   = begin + chunk; if (end > N) end = N;
    int s = 0;
    for (int i = begin; i < end; ++i) s += hist[i];
    partial[t] = s;
    __syncthreads();
    for (int off = 1; off < 1024; off <<= 1) {
        int v = (t >= off) ? partial[t - off] : 0;
        __syncthreads();
        partial[t] += v;
        __syncthreads();
    }
    int run = (t == 0) ? 0 : partial[t - 1];
    for (int i = begin; i < end; ++i) { base[i] = run; cursor[i] = run; run += hist[i]; }
    if (t == 1023) base[N] = partial[1023];
}

// ---------------- phase 3: MFMA edge MLP ----------------
// Per wave: 16-edge tile. D[ch][edge] = Wt x Ft via mfma_f32_16x16x32_bf16.
// msg_h row (64B): dword d=4g+i holds ch pair {4g+2i,4g+2i+1} (i<2) or {16+4g+2(i-2),...} (i>=2).
// msg_x row (16B): 3 f32 + pad.
__global__ __launch_bounds__(256) void egnn_edge_mfma(
    const float* __restrict__ node_feat,
    const float* __restrict__ coord,
    const float* __restrict__ edge_feat,
    const int*   __restrict__ src,
    const int*   __restrict__ dst,
    const float* __restrict__ We1,
    const float* __restrict__ be1,
    const float* __restrict__ We2,
    const float* __restrict__ be2,
    const float* __restrict__ Wc1,
    const float* __restrict__ bc1,
    const float* __restrict__ Wc2,
    int* __restrict__ cursor,
    unsigned int* __restrict__ msg_h,   // [E][16]
    unsigned int* __restrict__ msg_x,   // [E][4]
    int E)
{
    const int lane = threadIdx.x & 63;
    const int wid  = threadIdx.x >> 6;
    const int r    = lane & 15;   // edge slot / col
    const int g    = lane >> 4;   // k-group

    // ---- preload weight fragments + per-lane constants ----
    bf16x8 A1[3][2], A2[2], A3[2];
    #pragma unroll
    for (int kk = 0; kk < 3; ++kk) {
        A1[kk][0] = load_wT1(We1, be1, 32*kk + 8*g, r);
        A1[kk][1] = load_wT1(We1, be1, 32*kk + 8*g, 16 + r);
    }
    A2[0] = load_wT(We2, 8*g, r, 32);      A2[1] = load_wT(We2, 8*g, 16 + r, 32);
    A3[0] = load_wT(Wc1, 8*g, r, 32);      A3[1] = load_wT(Wc1, 8*g, 16 + r, 32);

    float be2v[8], bc1v[8], wc2v[8];
    #pragma unroll
    for (int h = 0; h < 2; ++h)
        #pragma unroll
        for (int q = 0; q < 4; ++q) {
            int ch = 16*h + 4*g + q;
            be2v[4*h+q] = be2[ch];
            bc1v[4*h+q] = bc1[ch];
            wc2v[4*h+q] = Wc2[ch];
        }

    const int  ntiles = (E + 15) >> 4;
    const int  nw     = gridDim.x * 4;
    const bool Hhi    = ((g >> 1) & 1) != 0;
    const int  s0L    = 32 * (g & 1) + r;
    const int  s1L    = s0L + 16;

    for (int tile = blockIdx.x * 4 + wid; tile < ntiles; tile += nw) {
        int e = tile * 16 + r;
        bool valid = (e < E);
        int ec = valid ? e : (E - 1);
        int s = src[ec], d = dst[ec];

        // ---- gather B fragments ----
        float fs[8], fd[8];
        {
            const float4* sp = reinterpret_cast<const float4*>(node_feat + (size_t)s * TIN + 8*g);
            float4 u0 = sp[0], u1 = sp[1];
            fs[0]=u0.x; fs[1]=u0.y; fs[2]=u0.z; fs[3]=u0.w;
            fs[4]=u1.x; fs[5]=u1.y; fs[6]=u1.z; fs[7]=u1.w;
            const float4* dp = reinterpret_cast<const float4*>(node_feat + (size_t)d * TIN + 8*g);
            float4 w0 = dp[0], w1 = dp[1];
            fd[0]=w0.x; fd[1]=w0.y; fd[2]=w0.z; fd[3]=w0.w;
            fd[4]=w1.x; fd[5]=w1.y; fd[6]=w1.z; fd[7]=w1.w;
        }

        float dx0 = coord[3*(size_t)s+0] - coord[3*(size_t)d+0];
        float dx1 = coord[3*(size_t)s+1] - coord[3*(size_t)d+1];
        float dx2 = coord[3*(size_t)s+2] - coord[3*(size_t)d+2];
        float radial = dx0*dx0 + dx1*dx1 + dx2*dx2;
        float invn = __builtin_amdgcn_rcpf(sqrtf(radial) + 1e-30f);
        dx0 *= invn; dx1 *= invn; dx2 *= invn;

        float fe[8];
        #pragma unroll
        for (int i = 0; i < 8; ++i) fe[i] = 0.0f;
        if (g == 0) {
            const float4* ep = reinterpret_cast<const float4*>(edge_feat + (size_t)ec * TEDGE);
            float4 e0 = ep[0], e1 = ep[1];
            fe[0]=radial; fe[1]=e0.x; fe[2]=e0.y; fe[3]=e0.z;
            fe[4]=e0.w;   fe[5]=e1.x; fe[6]=e1.y; fe[7]=e1.z;
        } else if (g == 1) {
            fe[0] = edge_feat[(size_t)ec * TEDGE + 7];   // k=72
            fe[1] = 1.0f;                                 // k=73 -> bias slot
        }

        bf16x8 Bk0 = pack8bf(fs), Bk1 = pack8bf(fd), Bk2 = pack8bf(fe);

        // ---- layer 1 (bias folded) ----
        f32x4 acc0 = {0.f,0.f,0.f,0.f}, acc1 = {0.f,0.f,0.f,0.f};
        acc0 = MFMA16(A1[0][0], Bk0, acc0);
        acc0 = MFMA16(A1[1][0], Bk1, acc0);
        acc0 = MFMA16(A1[2][0], Bk2, acc0);
        acc1 = MFMA16(A1[0][1], Bk0, acc1);
        acc1 = MFMA16(A1[1][1], Bk1, acc1);
        acc1 = MFMA16(A1[2][1], Bk2, acc1);

        unsigned int pk0 = cvtpk(silu_f(acc0[0]), silu_f(acc0[1]));
        unsigned int pk1 = cvtpk(silu_f(acc0[2]), silu_f(acc0[3]));
        unsigned int pk2 = cvtpk(silu_f(acc1[0]), silu_f(acc1[1]));
        unsigned int pk3 = cvtpk(silu_f(acc1[2]), silu_f(acc1[3]));

        // ---- transpose a1 -> B2 ----
        unsigned int al0 = __shfl(pk0, s0L, 64), al1 = __shfl(pk1, s0L, 64);
        unsigned int ah0 = __shfl(pk2, s0L, 64), ah1 = __shfl(pk3, s0L, 64);
        unsigned int bl0 = __shfl(pk0, s1L, 64), bl1 = __shfl(pk1, s1L, 64);
        unsigned int bh0 = __shfl(pk2, s1L, 64), bh1 = __shfl(pk3, s1L, 64);
        U4F B2u;
        B2u.u[0] = Hhi ? ah0 : al0;  B2u.u[1] = Hhi ? ah1 : al1;
        B2u.u[2] = Hhi ? bh0 : bl0;  B2u.u[3] = Hhi ? bh1 : bl1;

        // ---- layer 2 ----
        f32x4 m0, m1;
        #pragma unroll
        for (int q = 0; q < 4; ++q) { m0[q] = be2v[q]; m1[q] = be2v[4+q]; }
        m0 = MFMA16(A2[0], B2u.v, m0);
        m1 = MFMA16(A2[1], B2u.v, m1);

        unsigned int mpk0 = cvtpk(silu_f(m0[0]), silu_f(m0[1]));
        unsigned int mpk1 = cvtpk(silu_f(m0[2]), silu_f(m0[3]));
        unsigned int mpk2 = cvtpk(silu_f(m1[0]), silu_f(m1[1]));
        unsigned int mpk3 = cvtpk(silu_f(m1[2]), silu_f(m1[3]));

        // ---- transpose msg -> B3 ----
        unsigned int cl0 = __shfl(mpk0, s0L, 64), cl1 = __shfl(mpk1, s0L, 64);
        unsigned int ch0 = __shfl(mpk2, s0L, 64), ch1 = __shfl(mpk3, s0L, 64);
        unsigned int dl0 = __shfl(mpk0, s1L, 64), dl1 = __shfl(mpk1, s1L, 64);
        unsigned int dh0 = __shfl(mpk2, s1L, 64), dh1 = __shfl(mpk3, s1L, 64);
        U4F B3u;
        B3u.u[0] = Hhi ? ch0 : cl0;  B3u.u[1] = Hhi ? ch1 : cl1;
        B3u.u[2] = Hhi ? dh0 : dl0;  B3u.u[3] = Hhi ? dh1 : dl1;

        // ---- layer 3: coord gate ----
        f32x4 c0, c1;
        #pragma unroll
        for (int q = 0; q < 4; ++q) { c0[q] = bc1v[q]; c1[q] = bc1v[4+q]; }
        c0 = MFMA16(A3[0], B3u.v, c0);
        c1 = MFMA16(A3[1], B3u.v, c1);

        float gp = 0.0f;
        #pragma unroll
        for (int q = 0; q < 4; ++q) {
            gp = fmaf(silu_f(c0[q]), wc2v[q],   gp);
            gp = fmaf(silu_f(c1[q]), wc2v[4+q], gp);
        }
        gp += __shfl_xor(gp, 16, 64);
        gp += __shfl_xor(gp, 32, 64);

        // ---- scatter writes ----
        int pos = 0;
        if (g == 0 && valid) pos = atomicAdd(&cursor[d], 1);
        pos = __shfl(pos, r, 64);
        if (valid) {
            uint4 hv; hv.x = mpk0; hv.y = mpk1; hv.z = mpk2; hv.w = mpk3;
            *reinterpret_cast<uint4*>(msg_h + (size_t)pos * 16 + 4*g) = hv;
            if (g == 0) {
                uint4 xv;
                xv.x = __float_as_uint(gp * dx0);
                xv.y = __float_as_uint(gp * dx1);
                xv.z = __float_as_uint(gp * dx2);
                xv.w = 0u;
                *reinterpret_cast<uint4*>(msg_x + (size_t)pos * 4) = xv;
            }
        }
    }
}

// ---------------- phase 4: segment-sum, one wave per node ----------------
__global__ __launch_bounds__(256) void aggregate_kernel(
    const unsigned int* __restrict__ msg_h,
    const unsigned int* __restrict__ msg_x,
    const int* __restrict__ base,
    float* __restrict__ h_acc,   // [N][32]
    float* __restrict__ x_acc,   // [N][3]
    float* __restrict__ deg,     // [N]
    int N)
{
    int n    = (blockIdx.x * 256 + threadIdx.x) >> 6;  // node id (wave per node)
    int lane = threadIdx.x & 63;
    if (n >= N) return;

    int s = base[n], e = base[n+1];

    // ---- h: 4 rows per iteration, 256B contiguous ----
    int row = lane >> 4, dw = lane & 15;
    float sA = 0.0f, sB = 0.0f;
    for (int j = s; j < e; j += 4) {
        int jj = j + row;
        if (jj < e) {
            unsigned int u = msg_h[(size_t)jj * 16 + dw];
            sA += __uint_as_float((u & 0xFFFFu) << 16);
            sB += __uint_as_float(u & 0xFFFF0000u);
        }
    }
    sA += __shfl_xor(sA, 16, 64); sA += __shfl_xor(sA, 32, 64);
    sB += __shfl_xor(sB, 16, 64); sB += __shfl_xor(sB, 32, 64);
    if (lane < 16) {
        int g2 = dw >> 2, i = dw & 3;
        int ch = (i < 2) ? (4*g2 + 2*i) : (16 + 4*g2 + 2*(i-2));
        float2 v; v.x = sA; v.y = sB;
        *reinterpret_cast<float2*>(h_acc + (size_t)n * THID + ch) = v;
    }

    // ---- x: 16 rows per iteration ----
    int xrow = lane >> 2, xc = lane & 3;
    float sx = 0.0f;
    for (int j = s; j < e; j += 16) {
        int jj = j + xrow;
        if (jj < e && xc < 3) sx += __uint_as_float(msg_x[(size_t)jj * 4 + xc]);
    }
    sx += __shfl_xor(sx, 4, 64); sx += __shfl_xor(sx, 8, 64);
    sx += __shfl_xor(sx, 16, 64); sx += __shfl_xor(sx, 32, 64);
    if (lane < 3) x_acc[(size_t)n * 3 + lane] = sx;
    if (lane == 3) deg[n] = (float)(e - s);
}

// ---------------- fallback: atomic edge kernel (small-ws path) ----------------
__global__ __launch_bounds__(256) void egnn_edge_atomic(
    const float* __restrict__ node_feat,
    const float* __restrict__ coord,
    const float* __restrict__ edge_feat,
    const int*   __restrict__ src,
    const int*   __restrict__ dst,
    const float* __restrict__ We1,
    const float* __restrict__ be1,
    const float* __restrict__ We2,
    const float* __restrict__ be2,
    const float* __restrict__ Wc1,
    const float* __restrict__ bc1,
    const float* __restrict__ Wc2,
    float* __restrict__ h_acc,
    float* __restrict__ x_acc,
    float* __restrict__ deg,
    int E)
{
    int e = blockIdx.x * 256 + threadIdx.x;
    if (e >= E) return;
    int s = src[e];
    int d = dst[e];
    float dx0 = coord[3*(size_t)s+0] - coord[3*(size_t)d+0];
    float dx1 = coord[3*(size_t)s+1] - coord[3*(size_t)d+1];
    float dx2 = coord[3*(size_t)s+2] - coord[3*(size_t)d+2];
    float radial = dx0*dx0 + dx1*dx1 + dx2*dx2;
    float invn = 1.0f / (sqrtf(radial) + 1e-30f);
    dx0 *= invn; dx1 *= invn; dx2 *= invn;
    float f[73];
    #pragma unroll
    for (int i = 0; i < 32; ++i) f[i] = node_feat[(size_t)s*TIN + i];
    #pragma unroll
    for (int i = 0; i < 32; ++i) f[32+i] = node_feat[(size_t)d*TIN + i];
    f[64] = radial;
    #pragma unroll
    for (int i = 0; i < 8; ++i) f[65+i] = edge_feat[(size_t)e*TEDGE + i];
    float a1[THID];
    #pragma unroll
    for (int j = 0; j < THID; ++j) a1[j] = be1[j];
    for (int k = 0; k < 73; ++k) {
        float fk = f[k];
        #pragma unroll
        for (int j = 0; j < THID; ++j) a1[j] = fmaf(fk, We1[k*THID + j], a1[j]);
    }
    #pragma unroll
    for (int j = 0; j < THID; ++j) a1[j] = silu_f(a1[j]);
    float msg[THID];
    #pragma unroll
    for (int j = 0; j < THID; ++j) msg[j] = be2[j];
    for (int k = 0; k < THID; ++k) {
        float fk = a1[k];
        #pragma unroll
        for (int j = 0; j < THID; ++j) msg[j] = fmaf(fk, We2[k*THID + j], msg[j]);
    }
    #pragma unroll
    for (int j = 0; j < THID; ++j) msg[j] = silu_f(msg[j]);
    float c1[THID];
    #pragma unroll
    for (int j = 0; j < THID; ++j) c1[j] = bc1[j];
    for (int k = 0; k < THID; ++k) {
        float fk = msg[k];
        #pragma unroll
        for (int j = 0; j < THID; ++j) c1[j] = fmaf(fk, Wc1[k*THID + j], c1[j]);
    }
    float gate = 0.0f;
    #pragma unroll
    for (int j = 0; j < THID; ++j) gate = fmaf(silu_f(c1[j]), Wc2[j], gate);
    float* ha = h_acc + (size_t)d * THID;
    #pragma unroll
    for (int j = 0; j < THID; ++j) atomicAdd(ha + j, msg[j]);
    atomicAdd(x_acc + (size_t)d*3 + 0, gate * dx0);
    atomicAdd(x_acc + (size_t)d*3 + 1, gate * dx1);
    atomicAdd(x_acc + (size_t)d*3 + 2, gate * dx2);
    atomicAdd(deg + d, 1.0f);
}

// ---------------- phase 5: node update ----------------
__global__ __launch_bounds__(256) void egnn_node(
    const float* __restrict__ node_feat,
    const float* __restrict__ coord,
    const float* __restrict__ Wn1,
    const float* __restrict__ bn1,
    const float* __restrict__ Wn2,
    const float* __restrict__ bn2,
    const float* __restrict__ h_acc,
    const float* __restrict__ x_acc,
    const float* __restrict__ deg,
    float* __restrict__ out_h,
    float* __restrict__ out_x,
    int N)
{
    int n = blockIdx.x * 256 + threadIdx.x;
    if (n >= N) return;

    float f2[2*TIN];
    {
        const float4* p = reinterpret_cast<const float4*>(node_feat + (size_t)n * TIN);
        #pragma unroll
        for (int i = 0; i < TIN/4; ++i) {
            float4 v = p[i];
            f2[4*i+0]=v.x; f2[4*i+1]=v.y; f2[4*i+2]=v.z; f2[4*i+3]=v.w;
        }
    }
    {
        const float4* p = reinterpret_cast<const float4*>(h_acc + (size_t)n * THID);
        #pragma unroll
        for (int i = 0; i < THID/4; ++i) {
            float4 v = p[i];
            f2[TIN+4*i+0]=v.x; f2[TIN+4*i+1]=v.y; f2[TIN+4*i+2]=v.z; f2[TIN+4*i+3]=v.w;
        }
    }

    float a[THID];
    #pragma unroll
    for (int j = 0; j < THID; ++j) a[j] = bn1[j];
    #pragma unroll
    for (int k = 0; k < 2*TIN; ++k) {
        float fk = f2[k];
        #pragma unroll
        for (int j = 0; j < THID; ++j) a[j] = fmaf(fk, Wn1[k*THID + j], a[j]);
    }
    #pragma unroll
    for (int j = 0; j < THID; ++j) a[j] = silu_f(a[j]);

    float h[TOUT];
    #pragma unroll
    for (int j = 0; j < TOUT; ++j) h[j] = bn2[j];
    #pragma unroll
    for (int k = 0; k < THID; ++k) {
        float fk = a[k];
        #pragma unroll
        for (int j = 0; j < TOUT; ++j) h[j] = fmaf(fk, Wn2[k*TOUT + j], h[j]);
    }

    float4* po = reinterpret_cast<float4*>(out_h + (size_t)n * TOUT);
    #pragma unroll
    for (int i = 0; i < TOUT/4; ++i) {
        float4 v; v.x=h[4*i+0]; v.y=h[4*i+1]; v.z=h[4*i+2]; v.w=h[4*i+3];
        po[i] = v;
    }

    float dg = fmaxf(deg[n], 1.0f);
    float inv = __builtin_amdgcn_rcpf(dg);
    out_x[(size_t)n*3+0] = coord[(size_t)n*3+0] + x_acc[(size_t)n*3+0] * inv;
    out_x[(size_t)n*3+1] = coord[(size_t)n*3+1] + x_acc[(size_t)n*3+1] * inv;
    out_x[(size_t)n*3+2] = coord[(size_t)n*3+2] + x_acc[(size_t)n*3+2] * inv;
}

extern "C" void kernel_launch(void* const* d_in, const int* in_sizes, int n_in,
                              void* d_out, int out_size, void* d_ws, size_t ws_size,
                              hipStream_t stream) {
    const float* node_feat = (const float*)d_in[0];
    const float* coord     = (const float*)d_in[1];
    const float* edge_feat = (const float*)d_in[2];
    const int*   src       = (const int*)d_in[3];
    const int*   dst       = (const int*)d_in[4];
    const float* We1 = (const float*)d_in[5];
    const float* be1 = (const float*)d_in[6];
    const float* We2 = (const float*)d_in[7];
    const float* be2 = (const float*)d_in[8];
    const float* Wn1 = (const float*)d_in[9];
    const float* bn1 = (const float*)d_in[10];
    const float* Wn2 = (const float*)d_in[11];
    const float* bn2 = (const float*)d_in[12];
    const float* Wc1 = (const float*)d_in[13];
    const float* bc1 = (const float*)d_in[14];
    const float* Wc2 = (const float*)d_in[15];

    int N = in_sizes[0] / TIN;
    int E = in_sizes[3];

    float* out_h = (float*)d_out;
    float* out_x = out_h + (size_t)N * TOUT;

    // workspace layout: msg_h [E][16], msg_x [E][4], then accumulators / CSR
    unsigned int* msg_h = (unsigned int*)d_ws;
    unsigned int* msg_x = msg_h + (size_t)E * 16;
    float* h_acc = (float*)(msg_x + (size_t)E * 4);
    float* x_acc = h_acc + (size_t)N * THID;
    float* degv  = x_acc + (size_t)N * 3;
    int*   hist  = (int*)(degv + N);
    int*   basep = hist + N;
    int*   cursor = basep + (N + 1);
    size_t need = (size_t)((char*)(cursor + N) - (char*)d_ws);

    if (need <= ws_size) {
        hipMemsetAsync(hist, 0, (size_t)N * 4, stream);
        hist_kernel<<<(E + 255) / 256, 256, 0, stream>>>(dst, hist, E);
        scan_hist<<<1, 1024, 0, stream>>>(hist, basep, cursor, N);
        egnn_edge_mfma<<<2048, 256, 0, stream>>>(
            node_feat, coord, edge_feat, src, dst,
            We1, be1, We2, be2, Wc1, bc1, Wc2,
            cursor, msg_h, msg_x, E);
        aggregate_kernel<<<(int)(((size_t)N * 64 + 255) / 256), 256, 0, stream>>>(
            msg_h, msg_x, basep, h_acc, x_acc, degv, N);
        egnn_node<<<(N + 255) / 256, 256, 0, stream>>>(
            node_feat, coord, Wn1, bn1, Wn2, bn2,
            h_acc, x_acc, degv, out_h, out_x, N);
    } else {
        float* fh_acc = (float*)d_ws;
        float* fx_acc = fh_acc + (size_t)N * THID;
        float* fdeg   = fx_acc + (size_t)N * 3;
        hipMemsetAsync(d_ws, 0, sizeof(float) * (size_t)N * (THID + 3 + 1), stream);
        egnn_edge_atomic<<<(E + 255) / 256, 256, 0, stream>>>(
            node_feat, coord, edge_feat, src, dst,
            We1, be1, We2, be2, Wc1, bc1, Wc2,
            fh_acc, fx_acc, fdeg, E);
        egnn_node<<<(N + 255) / 256, 256, 0, stream>>>(
            node_feat, coord, Wn1, bn1, Wn2, bn2,
            fh_acc, fx_acc, fdeg, out_h, out_x, N);
    }
}

// Round 5
// 877.728 us; speedup vs baseline: 1.0374x; 1.0374x over previous
//
#include <hip/hip_runtime.h>
#include <math.h>

#define TIN   32
#define THID  32
#define TOUT  32
#define TEDGE 8

typedef __attribute__((ext_vector_type(8))) short bf16x8;
typedef __attribute__((ext_vector_type(4))) float f32x4;

#define MFMA16(a, b, c) __builtin_amdgcn_mfma_f32_16x16x32_bf16((a), (b), (c), 0, 0, 0)

// hardware packed f32->bf16 (RNE), 1 instruction
__device__ __forceinline__ unsigned int cvtpk(float lo, float hi) {
    unsigned int r;
    asm("v_cvt_pk_bf16_f32 %0, %1, %2" : "=v"(r) : "v"(lo), "v"(hi));
    return r;
}

__device__ __forceinline__ float silu_f(float x) {
    float e = __expf(-x);
    return x * __builtin_amdgcn_rcpf(1.0f + e);
}

union U4F { unsigned int u[4]; bf16x8 v; };
union U4Q { uint4 q; bf16x8 v; };

__device__ __forceinline__ bf16x8 pack8bf(const float* f) {
    U4F t;
    t.u[0] = cvtpk(f[0], f[1]);
    t.u[1] = cvtpk(f[2], f[3]);
    t.u[2] = cvtpk(f[4], f[5]);
    t.u[3] = cvtpk(f[6], f[7]);
    return t.v;
}

__device__ __forceinline__ bf16x8 load_wT(const float* __restrict__ W, int kbase, int ch, int Kreal) {
    float f[8];
    #pragma unroll
    for (int e = 0; e < 8; ++e) {
        int k = kbase + e;
        f[e] = (k < Kreal) ? W[k * 32 + ch] : 0.0f;
    }
    return pack8bf(f);
}
// layer-1 variant: k==73 carries be1[ch] (B-side supplies 1.0 there)
__device__ __forceinline__ bf16x8 load_wT1(const float* __restrict__ W, const float* __restrict__ bias,
                                           int kbase, int ch) {
    float f[8];
    #pragma unroll
    for (int e = 0; e < 8; ++e) {
        int k = kbase + e;
        f[e] = (k < 73) ? W[k * 32 + ch] : ((k == 73) ? bias[ch] : 0.0f);
    }
    return pack8bf(f);
}

// ---------------- phase 0a: node_feat f32 -> bf16 rows ----------------
__global__ __launch_bounds__(256) void conv_node_kernel(
    const float* __restrict__ nf, unsigned int* __restrict__ nb, int total /* N*16 */)
{
    int i = blockIdx.x * 256 + threadIdx.x;
    int stride = gridDim.x * 256;
    for (; i < total; i += stride) {
        float2 v = reinterpret_cast<const float2*>(nf)[i];
        nb[i] = cvtpk(v.x, v.y);
    }
}

// ---------------- phase 0b: coord [N,3] -> padded float4 ----------------
__global__ __launch_bounds__(256) void conv_coord_kernel(
    const float* __restrict__ c, float4* __restrict__ c4, int N)
{
    int i = blockIdx.x * 256 + threadIdx.x;
    int stride = gridDim.x * 256;
    for (; i < N; i += stride) {
        float4 v;
        v.x = c[3*(size_t)i+0]; v.y = c[3*(size_t)i+1]; v.z = c[3*(size_t)i+2]; v.w = 0.0f;
        c4[i] = v;
    }
}

// ---------------- phase 1: histogram of dst ----------------
__global__ __launch_bounds__(256) void hist_kernel(
    const int* __restrict__ dst, int* __restrict__ hist, int E)
{
    int e = blockIdx.x * 256 + threadIdx.x;
    if (e < E) atomicAdd(&hist[dst[e]], 1);
}

// ---------------- phase 2: exclusive scan (single block), writes base AND cursor ----------------
__global__ __launch_bounds__(1024) void scan_hist(
    const int* __restrict__ hist, int* __restrict__ base, int* __restrict__ cursor, int N)
{
    __shared__ int partial[1024];
    int t = threadIdx.x;
    int chunk = (N + 1023) / 1024;
    int begin = t * chunk;
    int end   = begin + chunk; if (end > N) end = N;
    int s = 0;
    for (int i = begin; i < end; ++i) s += hist[i];
    partial[t] = s;
    __syncthreads();
    for (int off = 1; off < 1024; off <<= 1) {
        int v = (t >= off) ? partial[t - off] : 0;
        __syncthreads();
        partial[t] += v;
        __syncthreads();
    }
    int run = (t == 0) ? 0 : partial[t - 1];
    for (int i = begin; i < end; ++i) { base[i] = run; cursor[i] = run; run += hist[i]; }
    if (t == 1023) base[N] = partial[1023];
}

// ---------------- phase 3: MFMA edge MLP (bf16 node rows, float4 coords) ----------------
__global__ __launch_bounds__(256) void egnn_edge_mfma(
    const unsigned int* __restrict__ node_bf,   // [N][16] uints (32 bf16)
    const float4* __restrict__ coord4,          // [N]
    const float* __restrict__ edge_feat,
    const int*   __restrict__ src,
    const int*   __restrict__ dst,
    const float* __restrict__ We1,
    const float* __restrict__ be1,
    const float* __restrict__ We2,
    const float* __restrict__ be2,
    const float* __restrict__ Wc1,
    const float* __restrict__ bc1,
    const float* __restrict__ Wc2,
    int* __restrict__ cursor,
    unsigned int* __restrict__ msg_h,   // [E][16]
    unsigned int* __restrict__ msg_x,   // [E][4]
    int E)
{
    const int lane = threadIdx.x & 63;
    const int wid  = threadIdx.x >> 6;
    const int r    = lane & 15;   // edge slot / col
    const int g    = lane >> 4;   // k-group

    // ---- preload weight fragments + per-lane constants ----
    bf16x8 A1[3][2], A2[2], A3[2];
    #pragma unroll
    for (int kk = 0; kk < 3; ++kk) {
        A1[kk][0] = load_wT1(We1, be1, 32*kk + 8*g, r);
        A1[kk][1] = load_wT1(We1, be1, 32*kk + 8*g, 16 + r);
    }
    A2[0] = load_wT(We2, 8*g, r, 32);      A2[1] = load_wT(We2, 8*g, 16 + r, 32);
    A3[0] = load_wT(Wc1, 8*g, r, 32);      A3[1] = load_wT(Wc1, 8*g, 16 + r, 32);

    float be2v[8], bc1v[8], wc2v[8];
    #pragma unroll
    for (int h = 0; h < 2; ++h)
        #pragma unroll
        for (int q = 0; q < 4; ++q) {
            int ch = 16*h + 4*g + q;
            be2v[4*h+q] = be2[ch];
            bc1v[4*h+q] = bc1[ch];
            wc2v[4*h+q] = Wc2[ch];
        }

    const int  ntiles = (E + 15) >> 4;
    const int  nw     = gridDim.x * 4;
    const bool Hhi    = ((g >> 1) & 1) != 0;
    const int  s0L    = 32 * (g & 1) + r;
    const int  s1L    = s0L + 16;

    for (int tile = blockIdx.x * 4 + wid; tile < ntiles; tile += nw) {
        int e = tile * 16 + r;
        bool valid = (e < E);
        int ec = valid ? e : (E - 1);
        int s = src[ec], d = dst[ec];

        // ---- gather node B fragments directly as bf16 (one 16B chunk per lane) ----
        U4Q Bs, Bd;
        Bs.q = reinterpret_cast<const uint4*>(node_bf + (size_t)s * 16)[g];
        Bd.q = reinterpret_cast<const uint4*>(node_bf + (size_t)d * 16)[g];

        // ---- geometry + edge fragment (g0/g1 lanes only) ----
        float dx0 = 0.f, dx1 = 0.f, dx2 = 0.f;
        unsigned int fe0 = 0u, fe1 = 0u, fe2 = 0u, fe3 = 0u;
        if (g == 0) {
            float4 cs = coord4[s];
            float4 cd = coord4[d];
            dx0 = cs.x - cd.x; dx1 = cs.y - cd.y; dx2 = cs.z - cd.z;
            float radial = dx0*dx0 + dx1*dx1 + dx2*dx2;
            float invn = __builtin_amdgcn_rcpf(sqrtf(radial) + 1e-30f);
            dx0 *= invn; dx1 *= invn; dx2 *= invn;
            const float4* ep = reinterpret_cast<const float4*>(edge_feat + (size_t)ec * TEDGE);
            float4 e0 = ep[0], e1 = ep[1];
            fe0 = cvtpk(radial, e0.x);
            fe1 = cvtpk(e0.y, e0.z);
            fe2 = cvtpk(e0.w, e1.x);
            fe3 = cvtpk(e1.y, e1.z);
        } else if (g == 1) {
            float ef7 = edge_feat[(size_t)ec * TEDGE + 7];  // k=72; k=73 -> bias 1.0
            fe0 = cvtpk(ef7, 1.0f);
        }
        U4F Bk2u;
        Bk2u.u[0] = fe0; Bk2u.u[1] = fe1; Bk2u.u[2] = fe2; Bk2u.u[3] = fe3;

        // ---- layer 1 (bias folded at k=73) ----
        f32x4 acc0 = {0.f,0.f,0.f,0.f}, acc1 = {0.f,0.f,0.f,0.f};
        acc0 = MFMA16(A1[0][0], Bs.v,   acc0);
        acc0 = MFMA16(A1[1][0], Bd.v,   acc0);
        acc0 = MFMA16(A1[2][0], Bk2u.v, acc0);
        acc1 = MFMA16(A1[0][1], Bs.v,   acc1);
        acc1 = MFMA16(A1[1][1], Bd.v,   acc1);
        acc1 = MFMA16(A1[2][1], Bk2u.v, acc1);

        unsigned int pk0 = cvtpk(silu_f(acc0[0]), silu_f(acc0[1]));
        unsigned int pk1 = cvtpk(silu_f(acc0[2]), silu_f(acc0[3]));
        unsigned int pk2 = cvtpk(silu_f(acc1[0]), silu_f(acc1[1]));
        unsigned int pk3 = cvtpk(silu_f(acc1[2]), silu_f(acc1[3]));

        // ---- transpose a1 -> B2 ----
        unsigned int al0 = __shfl(pk0, s0L, 64), al1 = __shfl(pk1, s0L, 64);
        unsigned int ah0 = __shfl(pk2, s0L, 64), ah1 = __shfl(pk3, s0L, 64);
        unsigned int bl0 = __shfl(pk0, s1L, 64), bl1 = __shfl(pk1, s1L, 64);
        unsigned int bh0 = __shfl(pk2, s1L, 64), bh1 = __shfl(pk3, s1L, 64);
        U4F B2u;
        B2u.u[0] = Hhi ? ah0 : al0;  B2u.u[1] = Hhi ? ah1 : al1;
        B2u.u[2] = Hhi ? bh0 : bl0;  B2u.u[3] = Hhi ? bh1 : bl1;

        // ---- layer 2 ----
        f32x4 m0, m1;
        #pragma unroll
        for (int q = 0; q < 4; ++q) { m0[q] = be2v[q]; m1[q] = be2v[4+q]; }
        m0 = MFMA16(A2[0], B2u.v, m0);
        m1 = MFMA16(A2[1], B2u.v, m1);

        unsigned int mpk0 = cvtpk(silu_f(m0[0]), silu_f(m0[1]));
        unsigned int mpk1 = cvtpk(silu_f(m0[2]), silu_f(m0[3]));
        unsigned int mpk2 = cvtpk(silu_f(m1[0]), silu_f(m1[1]));
        unsigned int mpk3 = cvtpk(silu_f(m1[2]), silu_f(m1[3]));

        // ---- transpose msg -> B3 ----
        unsigned int cl0 = __shfl(mpk0, s0L, 64), cl1 = __shfl(mpk1, s0L, 64);
        unsigned int ch0 = __shfl(mpk2, s0L, 64), ch1 = __shfl(mpk3, s0L, 64);
        unsigned int dl0 = __shfl(mpk0, s1L, 64), dl1 = __shfl(mpk1, s1L, 64);
        unsigned int dh0 = __shfl(mpk2, s1L, 64), dh1 = __shfl(mpk3, s1L, 64);
        U4F B3u;
        B3u.u[0] = Hhi ? ch0 : cl0;  B3u.u[1] = Hhi ? ch1 : cl1;
        B3u.u[2] = Hhi ? dh0 : dl0;  B3u.u[3] = Hhi ? dh1 : dl1;

        // ---- layer 3: coord gate ----
        f32x4 c0, c1;
        #pragma unroll
        for (int q = 0; q < 4; ++q) { c0[q] = bc1v[q]; c1[q] = bc1v[4+q]; }
        c0 = MFMA16(A3[0], B3u.v, c0);
        c1 = MFMA16(A3[1], B3u.v, c1);

        float gp = 0.0f;
        #pragma unroll
        for (int q = 0; q < 4; ++q) {
            gp = fmaf(silu_f(c0[q]), wc2v[q],   gp);
            gp = fmaf(silu_f(c1[q]), wc2v[4+q], gp);
        }
        gp += __shfl_xor(gp, 16, 64);
        gp += __shfl_xor(gp, 32, 64);

        // ---- scatter writes ----
        int pos = 0;
        if (g == 0 && valid) pos = atomicAdd(&cursor[d], 1);
        pos = __shfl(pos, r, 64);
        if (valid) {
            uint4 hv; hv.x = mpk0; hv.y = mpk1; hv.z = mpk2; hv.w = mpk3;
            *reinterpret_cast<uint4*>(msg_h + (size_t)pos * 16 + 4*g) = hv;
            if (g == 0) {
                uint4 xv;
                xv.x = __float_as_uint(gp * dx0);
                xv.y = __float_as_uint(gp * dx1);
                xv.z = __float_as_uint(gp * dx2);
                xv.w = 0u;
                *reinterpret_cast<uint4*>(msg_x + (size_t)pos * 4) = xv;
            }
        }
    }
}

// ---------------- phase 4: segment-sum, one wave per node ----------------
__global__ __launch_bounds__(256) void aggregate_kernel(
    const unsigned int* __restrict__ msg_h,
    const unsigned int* __restrict__ msg_x,
    const int* __restrict__ base,
    float* __restrict__ h_acc,   // [N][32]
    float* __restrict__ x_acc,   // [N][3]
    float* __restrict__ deg,     // [N]
    int N)
{
    int n    = (blockIdx.x * 256 + threadIdx.x) >> 6;  // node id (wave per node)
    int lane = threadIdx.x & 63;
    if (n >= N) return;

    int s = base[n], e = base[n+1];

    // ---- h: 4 rows per iteration, 256B contiguous ----
    int row = lane >> 4, dw = lane & 15;
    float sA = 0.0f, sB = 0.0f;
    for (int j = s; j < e; j += 4) {
        int jj = j + row;
        if (jj < e) {
            unsigned int u = msg_h[(size_t)jj * 16 + dw];
            sA += __uint_as_float((u & 0xFFFFu) << 16);
            sB += __uint_as_float(u & 0xFFFF0000u);
        }
    }
    sA += __shfl_xor(sA, 16, 64); sA += __shfl_xor(sA, 32, 64);
    sB += __shfl_xor(sB, 16, 64); sB += __shfl_xor(sB, 32, 64);
    if (lane < 16) {
        int g2 = dw >> 2, i = dw & 3;
        int ch = (i < 2) ? (4*g2 + 2*i) : (16 + 4*g2 + 2*(i-2));
        float2 v; v.x = sA; v.y = sB;
        *reinterpret_cast<float2*>(h_acc + (size_t)n * THID + ch) = v;
    }

    // ---- x: 16 rows per iteration ----
    int xrow = lane >> 2, xc = lane & 3;
    float sx = 0.0f;
    for (int j = s; j < e; j += 16) {
        int jj = j + xrow;
        if (jj < e && xc < 3) sx += __uint_as_float(msg_x[(size_t)jj * 4 + xc]);
    }
    sx += __shfl_xor(sx, 4, 64); sx += __shfl_xor(sx, 8, 64);
    sx += __shfl_xor(sx, 16, 64); sx += __shfl_xor(sx, 32, 64);
    if (lane < 3) x_acc[(size_t)n * 3 + lane] = sx;
    if (lane == 3) deg[n] = (float)(e - s);
}

// ---------------- fallback: atomic edge kernel (small-ws path) ----------------
__global__ __launch_bounds__(256) void egnn_edge_atomic(
    const float* __restrict__ node_feat,
    const float* __restrict__ coord,
    const float* __restrict__ edge_feat,
    const int*   __restrict__ src,
    const int*   __restrict__ dst,
    const float* __restrict__ We1,
    const float* __restrict__ be1,
    const float* __restrict__ We2,
    const float* __restrict__ be2,
    const float* __restrict__ Wc1,
    const float* __restrict__ bc1,
    const float* __restrict__ Wc2,
    float* __restrict__ h_acc,
    float* __restrict__ x_acc,
    float* __restrict__ deg,
    int E)
{
    int e = blockIdx.x * 256 + threadIdx.x;
    if (e >= E) return;
    int s = src[e];
    int d = dst[e];
    float dx0 = coord[3*(size_t)s+0] - coord[3*(size_t)d+0];
    float dx1 = coord[3*(size_t)s+1] - coord[3*(size_t)d+1];
    float dx2 = coord[3*(size_t)s+2] - coord[3*(size_t)d+2];
    float radial = dx0*dx0 + dx1*dx1 + dx2*dx2;
    float invn = 1.0f / (sqrtf(radial) + 1e-30f);
    dx0 *= invn; dx1 *= invn; dx2 *= invn;
    float f[73];
    #pragma unroll
    for (int i = 0; i < 32; ++i) f[i] = node_feat[(size_t)s*TIN + i];
    #pragma unroll
    for (int i = 0; i < 32; ++i) f[32+i] = node_feat[(size_t)d*TIN + i];
    f[64] = radial;
    #pragma unroll
    for (int i = 0; i < 8; ++i) f[65+i] = edge_feat[(size_t)e*TEDGE + i];
    float a1[THID];
    #pragma unroll
    for (int j = 0; j < THID; ++j) a1[j] = be1[j];
    for (int k = 0; k < 73; ++k) {
        float fk = f[k];
        #pragma unroll
        for (int j = 0; j < THID; ++j) a1[j] = fmaf(fk, We1[k*THID + j], a1[j]);
    }
    #pragma unroll
    for (int j = 0; j < THID; ++j) a1[j] = silu_f(a1[j]);
    float msg[THID];
    #pragma unroll
    for (int j = 0; j < THID; ++j) msg[j] = be2[j];
    for (int k = 0; k < THID; ++k) {
        float fk = a1[k];
        #pragma unroll
        for (int j = 0; j < THID; ++j) msg[j] = fmaf(fk, We2[k*THID + j], msg[j]);
    }
    #pragma unroll
    for (int j = 0; j < THID; ++j) msg[j] = silu_f(msg[j]);
    float c1[THID];
    #pragma unroll
    for (int j = 0; j < THID; ++j) c1[j] = bc1[j];
    for (int k = 0; k < THID; ++k) {
        float fk = msg[k];
        #pragma unroll
        for (int j = 0; j < THID; ++j) c1[j] = fmaf(fk, Wc1[k*THID + j], c1[j]);
    }
    float gate = 0.0f;
    #pragma unroll
    for (int j = 0; j < THID; ++j) gate = fmaf(silu_f(c1[j]), Wc2[j], gate);
    float* ha = h_acc + (size_t)d * THID;
    #pragma unroll
    for (int j = 0; j < THID; ++j) atomicAdd(ha + j, msg[j]);
    atomicAdd(x_acc + (size_t)d*3 + 0, gate * dx0);
    atomicAdd(x_acc + (size_t)d*3 + 1, gate * dx1);
    atomicAdd(x_acc + (size_t)d*3 + 2, gate * dx2);
    atomicAdd(deg + d, 1.0f);
}

// ---------------- phase 5: node update ----------------
__global__ __launch_bounds__(256) void egnn_node(
    const float* __restrict__ node_feat,
    const float* __restrict__ coord,
    const float* __restrict__ Wn1,
    const float* __restrict__ bn1,
    const float* __restrict__ Wn2,
    const float* __restrict__ bn2,
    const float* __restrict__ h_acc,
    const float* __restrict__ x_acc,
    const float* __restrict__ deg,
    float* __restrict__ out_h,
    float* __restrict__ out_x,
    int N)
{
    int n = blockIdx.x * 256 + threadIdx.x;
    if (n >= N) return;

    float f2[2*TIN];
    {
        const float4* p = reinterpret_cast<const float4*>(node_feat + (size_t)n * TIN);
        #pragma unroll
        for (int i = 0; i < TIN/4; ++i) {
            float4 v = p[i];
            f2[4*i+0]=v.x; f2[4*i+1]=v.y; f2[4*i+2]=v.z; f2[4*i+3]=v.w;
        }
    }
    {
        const float4* p = reinterpret_cast<const float4*>(h_acc + (size_t)n * THID);
        #pragma unroll
        for (int i = 0; i < THID/4; ++i) {
            float4 v = p[i];
            f2[TIN+4*i+0]=v.x; f2[TIN+4*i+1]=v.y; f2[TIN+4*i+2]=v.z; f2[TIN+4*i+3]=v.w;
        }
    }

    float a[THID];
    #pragma unroll
    for (int j = 0; j < THID; ++j) a[j] = bn1[j];
    #pragma unroll
    for (int k = 0; k < 2*TIN; ++k) {
        float fk = f2[k];
        #pragma unroll
        for (int j = 0; j < THID; ++j) a[j] = fmaf(fk, Wn1[k*THID + j], a[j]);
    }
    #pragma unroll
    for (int j = 0; j < THID; ++j) a[j] = silu_f(a[j]);

    float h[TOUT];
    #pragma unroll
    for (int j = 0; j < TOUT; ++j) h[j] = bn2[j];
    #pragma unroll
    for (int k = 0; k < THID; ++k) {
        float fk = a[k];
        #pragma unroll
        for (int j = 0; j < TOUT; ++j) h[j] = fmaf(fk, Wn2[k*TOUT + j], h[j]);
    }

    float4* po = reinterpret_cast<float4*>(out_h + (size_t)n * TOUT);
    #pragma unroll
    for (int i = 0; i < TOUT/4; ++i) {
        float4 v; v.x=h[4*i+0]; v.y=h[4*i+1]; v.z=h[4*i+2]; v.w=h[4*i+3];
        po[i] = v;
    }

    float dg = fmaxf(deg[n], 1.0f);
    float inv = __builtin_amdgcn_rcpf(dg);
    out_x[(size_t)n*3+0] = coord[(size_t)n*3+0] + x_acc[(size_t)n*3+0] * inv;
    out_x[(size_t)n*3+1] = coord[(size_t)n*3+1] + x_acc[(size_t)n*3+1] * inv;
    out_x[(size_t)n*3+2] = coord[(size_t)n*3+2] + x_acc[(size_t)n*3+2] * inv;
}

extern "C" void kernel_launch(void* const* d_in, const int* in_sizes, int n_in,
                              void* d_out, int out_size, void* d_ws, size_t ws_size,
                              hipStream_t stream) {
    const float* node_feat = (const float*)d_in[0];
    const float* coord     = (const float*)d_in[1];
    const float* edge_feat = (const float*)d_in[2];
    const int*   src       = (const int*)d_in[3];
    const int*   dst       = (const int*)d_in[4];
    const float* We1 = (const float*)d_in[5];
    const float* be1 = (const float*)d_in[6];
    const float* We2 = (const float*)d_in[7];
    const float* be2 = (const float*)d_in[8];
    const float* Wn1 = (const float*)d_in[9];
    const float* bn1 = (const float*)d_in[10];
    const float* Wn2 = (const float*)d_in[11];
    const float* bn2 = (const float*)d_in[12];
    const float* Wc1 = (const float*)d_in[13];
    const float* bc1 = (const float*)d_in[14];
    const float* Wc2 = (const float*)d_in[15];

    int N = in_sizes[0] / TIN;
    int E = in_sizes[3];

    float* out_h = (float*)d_out;
    float* out_x = out_h + (size_t)N * TOUT;

    // workspace layout (16B-aligned blocks first)
    unsigned int* msg_h   = (unsigned int*)d_ws;             // E*16 uints
    unsigned int* msg_x   = msg_h + (size_t)E * 16;          // E*4 uints
    float4*       coord4  = (float4*)(msg_x + (size_t)E*4);  // N
    unsigned int* node_bf = (unsigned int*)(coord4 + N);     // N*16 uints
    float* h_acc = (float*)(node_bf + (size_t)N * 16);
    float* x_acc = h_acc + (size_t)N * THID;
    float* degv  = x_acc + (size_t)N * 3;
    int*   hist  = (int*)(degv + N);
    int*   basep = hist + N;
    int*   cursor = basep + (N + 1);
    size_t need = (size_t)((char*)(cursor + N) - (char*)d_ws);

    if (need <= ws_size) {
        int nconv = N * 16;
        conv_node_kernel<<<2048, 256, 0, stream>>>(node_feat, node_bf, nconv);
        conv_coord_kernel<<<(N + 255) / 256, 256, 0, stream>>>(coord, coord4, N);
        hipMemsetAsync(hist, 0, (size_t)N * 4, stream);
        hist_kernel<<<(E + 255) / 256, 256, 0, stream>>>(dst, hist, E);
        scan_hist<<<1, 1024, 0, stream>>>(hist, basep, cursor, N);
        egnn_edge_mfma<<<2048, 256, 0, stream>>>(
            node_bf, coord4, edge_feat, src, dst,
            We1, be1, We2, be2, Wc1, bc1, Wc2,
            cursor, msg_h, msg_x, E);
        aggregate_kernel<<<(int)(((size_t)N * 64 + 255) / 256), 256, 0, stream>>>(
            msg_h, msg_x, basep, h_acc, x_acc, degv, N);
        egnn_node<<<(N + 255) / 256, 256, 0, stream>>>(
            node_feat, coord, Wn1, bn1, Wn2, bn2,
            h_acc, x_acc, degv, out_h, out_x, N);
    } else {
        float* fh_acc = (float*)d_ws;
        float* fx_acc = fh_acc + (size_t)N * THID;
        float* fdeg   = fx_acc + (size_t)N * 3;
        hipMemsetAsync(d_ws, 0, sizeof(float) * (size_t)N * (THID + 3 + 1), stream);
        egnn_edge_atomic<<<(E + 255) / 256, 256, 0, stream>>>(
            node_feat, coord, edge_feat, src, dst,
            We1, be1, We2, be2, Wc1, bc1, Wc2,
            fh_acc, fx_acc, fdeg, E);
        egnn_node<<<(N + 255) / 256, 256, 0, stream>>>(
            node_feat, coord, Wn1, bn1, Wn2, bn2,
            fh_acc, fx_acc, fdeg, out_h, out_x, N);
    }
}

// Round 6
// 709.639 us; speedup vs baseline: 1.2831x; 1.2369x over previous
//
#include <hip/hip_runtime.h>
#include <math.h>

#define TIN   32
#define THID  32
#define TOUT  32
#define TEDGE 8

typedef __attribute__((ext_vector_type(8))) short bf16x8;
typedef __attribute__((ext_vector_type(4))) float f32x4;

#define MFMA16(a, b, c) __builtin_amdgcn_mfma_f32_16x16x32_bf16((a), (b), (c), 0, 0, 0)

// hardware packed f32->bf16 (RNE), 1 instruction
__device__ __forceinline__ unsigned int cvtpk(float lo, float hi) {
    unsigned int r;
    asm("v_cvt_pk_bf16_f32 %0, %1, %2" : "=v"(r) : "v"(lo), "v"(hi));
    return r;
}

__device__ __forceinline__ float silu_f(float x) {
    float e = __expf(-x);
    return x * __builtin_amdgcn_rcpf(1.0f + e);
}

union U4F { unsigned int u[4]; bf16x8 v; };
union U4Q { uint4 q; bf16x8 v; };

__device__ __forceinline__ bf16x8 pack8bf(const float* f) {
    U4F t;
    t.u[0] = cvtpk(f[0], f[1]);
    t.u[1] = cvtpk(f[2], f[3]);
    t.u[2] = cvtpk(f[4], f[5]);
    t.u[3] = cvtpk(f[6], f[7]);
    return t.v;
}

__device__ __forceinline__ bf16x8 load_wT(const float* __restrict__ W, int kbase, int ch, int Kreal) {
    float f[8];
    #pragma unroll
    for (int e = 0; e < 8; ++e) {
        int k = kbase + e;
        f[e] = (k < Kreal) ? W[k * 32 + ch] : 0.0f;
    }
    return pack8bf(f);
}
// layer-1 variant: k==73 carries be1[ch] (B-side supplies 1.0 there)
__device__ __forceinline__ bf16x8 load_wT1(const float* __restrict__ W, const float* __restrict__ bias,
                                           int kbase, int ch) {
    float f[8];
    #pragma unroll
    for (int e = 0; e < 8; ++e) {
        int k = kbase + e;
        f[e] = (k < 73) ? W[k * 32 + ch] : ((k == 73) ? bias[ch] : 0.0f);
    }
    return pack8bf(f);
}

// ---------------- phase 0a: node_feat f32 -> bf16 rows ----------------
__global__ __launch_bounds__(256) void conv_node_kernel(
    const float* __restrict__ nf, unsigned int* __restrict__ nb, int total /* N*16 */)
{
    int i = blockIdx.x * 256 + threadIdx.x;
    int stride = gridDim.x * 256;
    for (; i < total; i += stride) {
        float2 v = reinterpret_cast<const float2*>(nf)[i];
        nb[i] = cvtpk(v.x, v.y);
    }
}

// ---------------- phase 0b: coord [N,3] -> padded float4 ----------------
__global__ __launch_bounds__(256) void conv_coord_kernel(
    const float* __restrict__ c, float4* __restrict__ c4, int N)
{
    int i = blockIdx.x * 256 + threadIdx.x;
    int stride = gridDim.x * 256;
    for (; i < N; i += stride) {
        float4 v;
        v.x = c[3*(size_t)i+0]; v.y = c[3*(size_t)i+1]; v.z = c[3*(size_t)i+2]; v.w = 0.0f;
        c4[i] = v;
    }
}

// ---------------- phase 1: rank pass (hist + per-edge rank in ONE atomic pass) ----------------
__global__ __launch_bounds__(256) void rank_kernel(
    const int* __restrict__ dst, int* __restrict__ cnt, int* __restrict__ pos_raw, int E)
{
    int e = blockIdx.x * 256 + threadIdx.x;
    if (e < E) pos_raw[e] = atomicAdd(&cnt[dst[e]], 1);
}

// ---------------- phase 2: coalesced tiled exclusive scan (single block, 16 waves) ----------------
__global__ __launch_bounds__(1024) void scan_kernel(
    const int* __restrict__ hist, int* __restrict__ base, int N)
{
    __shared__ int wsum[16];
    __shared__ int carry_s;
    int t = threadIdx.x, lane = t & 63, w = t >> 6;
    if (t == 0) carry_s = 0;
    __syncthreads();
    int ntiles = (N + 1023) >> 10;
    for (int tt = 0; tt < ntiles; ++tt) {
        int i = (tt << 10) + t;
        int v = (i < N) ? hist[i] : 0;
        // wave inclusive scan
        int x = v;
        #pragma unroll
        for (int off = 1; off < 64; off <<= 1) {
            int y = __shfl_up(x, off, 64);
            if (lane >= off) x += y;
        }
        if (lane == 63) wsum[w] = x;
        __syncthreads();
        int woff = 0, total = 0;
        #pragma unroll
        for (int k = 0; k < 16; ++k) {
            int s = wsum[k];
            woff += (k < w) ? s : 0;
            total += s;
        }
        int c = carry_s;
        if (i < N) base[i] = c + woff + x - v;   // exclusive prefix
        __syncthreads();
        if (t == 0) carry_s = c + total;
        __syncthreads();
    }
    if (t == 0) base[N] = carry_s;
}

// ---------------- phase 3: MFMA edge MLP (atomic-free scatter via precomputed rank) ----------------
__global__ __launch_bounds__(256) void egnn_edge_mfma(
    const unsigned int* __restrict__ node_bf,   // [N][16] uints (32 bf16)
    const float4* __restrict__ coord4,          // [N]
    const float* __restrict__ edge_feat,
    const int*   __restrict__ src,
    const int*   __restrict__ dst,
    const int*   __restrict__ pos_raw,          // [E] rank within dst
    const int*   __restrict__ baseArr,          // [N+1] CSR offsets
    const float* __restrict__ We1,
    const float* __restrict__ be1,
    const float* __restrict__ We2,
    const float* __restrict__ be2,
    const float* __restrict__ Wc1,
    const float* __restrict__ bc1,
    const float* __restrict__ Wc2,
    unsigned int* __restrict__ msg_h,   // [E][16]
    unsigned int* __restrict__ msg_x,   // [E][4]
    int E)
{
    const int lane = threadIdx.x & 63;
    const int wid  = threadIdx.x >> 6;
    const int r    = lane & 15;   // edge slot / col
    const int g    = lane >> 4;   // k-group

    // ---- preload weight fragments + per-lane constants ----
    bf16x8 A1[3][2], A2[2], A3[2];
    #pragma unroll
    for (int kk = 0; kk < 3; ++kk) {
        A1[kk][0] = load_wT1(We1, be1, 32*kk + 8*g, r);
        A1[kk][1] = load_wT1(We1, be1, 32*kk + 8*g, 16 + r);
    }
    A2[0] = load_wT(We2, 8*g, r, 32);      A2[1] = load_wT(We2, 8*g, 16 + r, 32);
    A3[0] = load_wT(Wc1, 8*g, r, 32);      A3[1] = load_wT(Wc1, 8*g, 16 + r, 32);

    float be2v[8], bc1v[8], wc2v[8];
    #pragma unroll
    for (int h = 0; h < 2; ++h)
        #pragma unroll
        for (int q = 0; q < 4; ++q) {
            int ch = 16*h + 4*g + q;
            be2v[4*h+q] = be2[ch];
            bc1v[4*h+q] = bc1[ch];
            wc2v[4*h+q] = Wc2[ch];
        }

    const int  ntiles = (E + 15) >> 4;
    const int  nw     = gridDim.x * 4;
    const bool Hhi    = ((g >> 1) & 1) != 0;
    const int  s0L    = 32 * (g & 1) + r;
    const int  s1L    = s0L + 16;

    for (int tile = blockIdx.x * 4 + wid; tile < ntiles; tile += nw) {
        int e = tile * 16 + r;
        bool valid = (e < E);
        int ec = valid ? e : (E - 1);
        int s = src[ec], d = dst[ec];

        // scatter position (atomic-free; broadcast across the 4 g-lanes)
        int pos = baseArr[d] + pos_raw[ec];

        // ---- gather node B fragments directly as bf16 (one 16B chunk per lane) ----
        U4Q Bs, Bd;
        Bs.q = reinterpret_cast<const uint4*>(node_bf + (size_t)s * 16)[g];
        Bd.q = reinterpret_cast<const uint4*>(node_bf + (size_t)d * 16)[g];

        // ---- geometry + edge fragment (g0/g1 lanes only) ----
        float dx0 = 0.f, dx1 = 0.f, dx2 = 0.f;
        unsigned int fe0 = 0u, fe1 = 0u, fe2 = 0u, fe3 = 0u;
        if (g == 0) {
            float4 cs = coord4[s];
            float4 cd = coord4[d];
            dx0 = cs.x - cd.x; dx1 = cs.y - cd.y; dx2 = cs.z - cd.z;
            float radial = dx0*dx0 + dx1*dx1 + dx2*dx2;
            float invn = __builtin_amdgcn_rcpf(sqrtf(radial) + 1e-30f);
            dx0 *= invn; dx1 *= invn; dx2 *= invn;
            const float4* ep = reinterpret_cast<const float4*>(edge_feat + (size_t)ec * TEDGE);
            float4 e0 = ep[0], e1 = ep[1];
            fe0 = cvtpk(radial, e0.x);
            fe1 = cvtpk(e0.y, e0.z);
            fe2 = cvtpk(e0.w, e1.x);
            fe3 = cvtpk(e1.y, e1.z);
        } else if (g == 1) {
            float ef7 = edge_feat[(size_t)ec * TEDGE + 7];  // k=72; k=73 -> bias 1.0
            fe0 = cvtpk(ef7, 1.0f);
        }
        U4F Bk2u;
        Bk2u.u[0] = fe0; Bk2u.u[1] = fe1; Bk2u.u[2] = fe2; Bk2u.u[3] = fe3;

        // ---- layer 1 (bias folded at k=73) ----
        f32x4 acc0 = {0.f,0.f,0.f,0.f}, acc1 = {0.f,0.f,0.f,0.f};
        acc0 = MFMA16(A1[0][0], Bs.v,   acc0);
        acc0 = MFMA16(A1[1][0], Bd.v,   acc0);
        acc0 = MFMA16(A1[2][0], Bk2u.v, acc0);
        acc1 = MFMA16(A1[0][1], Bs.v,   acc1);
        acc1 = MFMA16(A1[1][1], Bd.v,   acc1);
        acc1 = MFMA16(A1[2][1], Bk2u.v, acc1);

        unsigned int pk0 = cvtpk(silu_f(acc0[0]), silu_f(acc0[1]));
        unsigned int pk1 = cvtpk(silu_f(acc0[2]), silu_f(acc0[3]));
        unsigned int pk2 = cvtpk(silu_f(acc1[0]), silu_f(acc1[1]));
        unsigned int pk3 = cvtpk(silu_f(acc1[2]), silu_f(acc1[3]));

        // ---- transpose a1 -> B2 ----
        unsigned int al0 = __shfl(pk0, s0L, 64), al1 = __shfl(pk1, s0L, 64);
        unsigned int ah0 = __shfl(pk2, s0L, 64), ah1 = __shfl(pk3, s0L, 64);
        unsigned int bl0 = __shfl(pk0, s1L, 64), bl1 = __shfl(pk1, s1L, 64);
        unsigned int bh0 = __shfl(pk2, s1L, 64), bh1 = __shfl(pk3, s1L, 64);
        U4F B2u;
        B2u.u[0] = Hhi ? ah0 : al0;  B2u.u[1] = Hhi ? ah1 : al1;
        B2u.u[2] = Hhi ? bh0 : bl0;  B2u.u[3] = Hhi ? bh1 : bl1;

        // ---- layer 2 ----
        f32x4 m0, m1;
        #pragma unroll
        for (int q = 0; q < 4; ++q) { m0[q] = be2v[q]; m1[q] = be2v[4+q]; }
        m0 = MFMA16(A2[0], B2u.v, m0);
        m1 = MFMA16(A2[1], B2u.v, m1);

        unsigned int mpk0 = cvtpk(silu_f(m0[0]), silu_f(m0[1]));
        unsigned int mpk1 = cvtpk(silu_f(m0[2]), silu_f(m0[3]));
        unsigned int mpk2 = cvtpk(silu_f(m1[0]), silu_f(m1[1]));
        unsigned int mpk3 = cvtpk(silu_f(m1[2]), silu_f(m1[3]));

        // ---- transpose msg -> B3 ----
        unsigned int cl0 = __shfl(mpk0, s0L, 64), cl1 = __shfl(mpk1, s0L, 64);
        unsigned int ch0 = __shfl(mpk2, s0L, 64), ch1 = __shfl(mpk3, s0L, 64);
        unsigned int dl0 = __shfl(mpk0, s1L, 64), dl1 = __shfl(mpk1, s1L, 64);
        unsigned int dh0 = __shfl(mpk2, s1L, 64), dh1 = __shfl(mpk3, s1L, 64);
        U4F B3u;
        B3u.u[0] = Hhi ? ch0 : cl0;  B3u.u[1] = Hhi ? ch1 : cl1;
        B3u.u[2] = Hhi ? dh0 : dl0;  B3u.u[3] = Hhi ? dh1 : dl1;

        // ---- layer 3: coord gate ----
        f32x4 c0, c1;
        #pragma unroll
        for (int q = 0; q < 4; ++q) { c0[q] = bc1v[q]; c1[q] = bc1v[4+q]; }
        c0 = MFMA16(A3[0], B3u.v, c0);
        c1 = MFMA16(A3[1], B3u.v, c1);

        float gp = 0.0f;
        #pragma unroll
        for (int q = 0; q < 4; ++q) {
            gp = fmaf(silu_f(c0[q]), wc2v[q],   gp);
            gp = fmaf(silu_f(c1[q]), wc2v[4+q], gp);
        }
        gp += __shfl_xor(gp, 16, 64);
        gp += __shfl_xor(gp, 32, 64);

        // ---- scatter writes (atomic-free) ----
        if (valid) {
            uint4 hv; hv.x = mpk0; hv.y = mpk1; hv.z = mpk2; hv.w = mpk3;
            *reinterpret_cast<uint4*>(msg_h + (size_t)pos * 16 + 4*g) = hv;
            if (g == 0) {
                uint4 xv;
                xv.x = __float_as_uint(gp * dx0);
                xv.y = __float_as_uint(gp * dx1);
                xv.z = __float_as_uint(gp * dx2);
                xv.w = 0u;
                *reinterpret_cast<uint4*>(msg_x + (size_t)pos * 4) = xv;
            }
        }
    }
}

// ---------------- phase 4: segment-sum, one wave per node ----------------
__global__ __launch_bounds__(256) void aggregate_kernel(
    const unsigned int* __restrict__ msg_h,
    const unsigned int* __restrict__ msg_x,
    const int* __restrict__ base,
    float* __restrict__ h_acc,   // [N][32]
    float* __restrict__ x_acc,   // [N][3]
    float* __restrict__ deg,     // [N]
    int N)
{
    int n    = (blockIdx.x * 256 + threadIdx.x) >> 6;  // node id (wave per node)
    int lane = threadIdx.x & 63;
    if (n >= N) return;

    int s = base[n], e = base[n+1];

    // ---- h: 4 rows per iteration, 256B contiguous ----
    int row = lane >> 4, dw = lane & 15;
    float sA = 0.0f, sB = 0.0f;
    for (int j = s; j < e; j += 4) {
        int jj = j + row;
        if (jj < e) {
            unsigned int u = msg_h[(size_t)jj * 16 + dw];
            sA += __uint_as_float((u & 0xFFFFu) << 16);
            sB += __uint_as_float(u & 0xFFFF0000u);
        }
    }
    sA += __shfl_xor(sA, 16, 64); sA += __shfl_xor(sA, 32, 64);
    sB += __shfl_xor(sB, 16, 64); sB += __shfl_xor(sB, 32, 64);
    if (lane < 16) {
        int g2 = dw >> 2, i = dw & 3;
        int ch = (i < 2) ? (4*g2 + 2*i) : (16 + 4*g2 + 2*(i-2));
        float2 v; v.x = sA; v.y = sB;
        *reinterpret_cast<float2*>(h_acc + (size_t)n * THID + ch) = v;
    }

    // ---- x: 16 rows per iteration ----
    int xrow = lane >> 2, xc = lane & 3;
    float sx = 0.0f;
    for (int j = s; j < e; j += 16) {
        int jj = j + xrow;
        if (jj < e && xc < 3) sx += __uint_as_float(msg_x[(size_t)jj * 4 + xc]);
    }
    sx += __shfl_xor(sx, 4, 64); sx += __shfl_xor(sx, 8, 64);
    sx += __shfl_xor(sx, 16, 64); sx += __shfl_xor(sx, 32, 64);
    if (lane < 3) x_acc[(size_t)n * 3 + lane] = sx;
    if (lane == 3) deg[n] = (float)(e - s);
}

// ---------------- fallback: atomic edge kernel (small-ws path) ----------------
__global__ __launch_bounds__(256) void egnn_edge_atomic(
    const float* __restrict__ node_feat,
    const float* __restrict__ coord,
    const float* __restrict__ edge_feat,
    const int*   __restrict__ src,
    const int*   __restrict__ dst,
    const float* __restrict__ We1,
    const float* __restrict__ be1,
    const float* __restrict__ We2,
    const float* __restrict__ be2,
    const float* __restrict__ Wc1,
    const float* __restrict__ bc1,
    const float* __restrict__ Wc2,
    float* __restrict__ h_acc,
    float* __restrict__ x_acc,
    float* __restrict__ deg,
    int E)
{
    int e = blockIdx.x * 256 + threadIdx.x;
    if (e >= E) return;
    int s = src[e];
    int d = dst[e];
    float dx0 = coord[3*(size_t)s+0] - coord[3*(size_t)d+0];
    float dx1 = coord[3*(size_t)s+1] - coord[3*(size_t)d+1];
    float dx2 = coord[3*(size_t)s+2] - coord[3*(size_t)d+2];
    float radial = dx0*dx0 + dx1*dx1 + dx2*dx2;
    float invn = 1.0f / (sqrtf(radial) + 1e-30f);
    dx0 *= invn; dx1 *= invn; dx2 *= invn;
    float f[73];
    #pragma unroll
    for (int i = 0; i < 32; ++i) f[i] = node_feat[(size_t)s*TIN + i];
    #pragma unroll
    for (int i = 0; i < 32; ++i) f[32+i] = node_feat[(size_t)d*TIN + i];
    f[64] = radial;
    #pragma unroll
    for (int i = 0; i < 8; ++i) f[65+i] = edge_feat[(size_t)e*TEDGE + i];
    float a1[THID];
    #pragma unroll
    for (int j = 0; j < THID; ++j) a1[j] = be1[j];
    for (int k = 0; k < 73; ++k) {
        float fk = f[k];
        #pragma unroll
        for (int j = 0; j < THID; ++j) a1[j] = fmaf(fk, We1[k*THID + j], a1[j]);
    }
    #pragma unroll
    for (int j = 0; j < THID; ++j) a1[j] = silu_f(a1[j]);
    float msg[THID];
    #pragma unroll
    for (int j = 0; j < THID; ++j) msg[j] = be2[j];
    for (int k = 0; k < THID; ++k) {
        float fk = a1[k];
        #pragma unroll
        for (int j = 0; j < THID; ++j) msg[j] = fmaf(fk, We2[k*THID + j], msg[j]);
    }
    #pragma unroll
    for (int j = 0; j < THID; ++j) msg[j] = silu_f(msg[j]);
    float c1[THID];
    #pragma unroll
    for (int j = 0; j < THID; ++j) c1[j] = bc1[j];
    for (int k = 0; k < THID; ++k) {
        float fk = msg[k];
        #pragma unroll
        for (int j = 0; j < THID; ++j) c1[j] = fmaf(fk, Wc1[k*THID + j], c1[j]);
    }
    float gate = 0.0f;
    #pragma unroll
    for (int j = 0; j < THID; ++j) gate = fmaf(silu_f(c1[j]), Wc2[j], gate);
    float* ha = h_acc + (size_t)d * THID;
    #pragma unroll
    for (int j = 0; j < THID; ++j) atomicAdd(ha + j, msg[j]);
    atomicAdd(x_acc + (size_t)d*3 + 0, gate * dx0);
    atomicAdd(x_acc + (size_t)d*3 + 1, gate * dx1);
    atomicAdd(x_acc + (size_t)d*3 + 2, gate * dx2);
    atomicAdd(deg + d, 1.0f);
}

// ---------------- phase 5: node update ----------------
__global__ __launch_bounds__(256) void egnn_node(
    const float* __restrict__ node_feat,
    const float* __restrict__ coord,
    const float* __restrict__ Wn1,
    const float* __restrict__ bn1,
    const float* __restrict__ Wn2,
    const float* __restrict__ bn2,
    const float* __restrict__ h_acc,
    const float* __restrict__ x_acc,
    const float* __restrict__ deg,
    float* __restrict__ out_h,
    float* __restrict__ out_x,
    int N)
{
    int n = blockIdx.x * 256 + threadIdx.x;
    if (n >= N) return;

    float f2[2*TIN];
    {
        const float4* p = reinterpret_cast<const float4*>(node_feat + (size_t)n * TIN);
        #pragma unroll
        for (int i = 0; i < TIN/4; ++i) {
            float4 v = p[i];
            f2[4*i+0]=v.x; f2[4*i+1]=v.y; f2[4*i+2]=v.z; f2[4*i+3]=v.w;
        }
    }
    {
        const float4* p = reinterpret_cast<const float4*>(h_acc + (size_t)n * THID);
        #pragma unroll
        for (int i = 0; i < THID/4; ++i) {
            float4 v = p[i];
            f2[TIN+4*i+0]=v.x; f2[TIN+4*i+1]=v.y; f2[TIN+4*i+2]=v.z; f2[TIN+4*i+3]=v.w;
        }
    }

    float a[THID];
    #pragma unroll
    for (int j = 0; j < THID; ++j) a[j] = bn1[j];
    #pragma unroll
    for (int k = 0; k < 2*TIN; ++k) {
        float fk = f2[k];
        #pragma unroll
        for (int j = 0; j < THID; ++j) a[j] = fmaf(fk, Wn1[k*THID + j], a[j]);
    }
    #pragma unroll
    for (int j = 0; j < THID; ++j) a[j] = silu_f(a[j]);

    float h[TOUT];
    #pragma unroll
    for (int j = 0; j < TOUT; ++j) h[j] = bn2[j];
    #pragma unroll
    for (int k = 0; k < THID; ++k) {
        float fk = a[k];
        #pragma unroll
        for (int j = 0; j < TOUT; ++j) h[j] = fmaf(fk, Wn2[k*TOUT + j], h[j]);
    }

    float4* po = reinterpret_cast<float4*>(out_h + (size_t)n * TOUT);
    #pragma unroll
    for (int i = 0; i < TOUT/4; ++i) {
        float4 v; v.x=h[4*i+0]; v.y=h[4*i+1]; v.z=h[4*i+2]; v.w=h[4*i+3];
        po[i] = v;
    }

    float dg = fmaxf(deg[n], 1.0f);
    float inv = __builtin_amdgcn_rcpf(dg);
    out_x[(size_t)n*3+0] = coord[(size_t)n*3+0] + x_acc[(size_t)n*3+0] * inv;
    out_x[(size_t)n*3+1] = coord[(size_t)n*3+1] + x_acc[(size_t)n*3+1] * inv;
    out_x[(size_t)n*3+2] = coord[(size_t)n*3+2] + x_acc[(size_t)n*3+2] * inv;
}

extern "C" void kernel_launch(void* const* d_in, const int* in_sizes, int n_in,
                              void* d_out, int out_size, void* d_ws, size_t ws_size,
                              hipStream_t stream) {
    const float* node_feat = (const float*)d_in[0];
    const float* coord     = (const float*)d_in[1];
    const float* edge_feat = (const float*)d_in[2];
    const int*   src       = (const int*)d_in[3];
    const int*   dst       = (const int*)d_in[4];
    const float* We1 = (const float*)d_in[5];
    const float* be1 = (const float*)d_in[6];
    const float* We2 = (const float*)d_in[7];
    const float* be2 = (const float*)d_in[8];
    const float* Wn1 = (const float*)d_in[9];
    const float* bn1 = (const float*)d_in[10];
    const float* Wn2 = (const float*)d_in[11];
    const float* bn2 = (const float*)d_in[12];
    const float* Wc1 = (const float*)d_in[13];
    const float* bc1 = (const float*)d_in[14];
    const float* Wc2 = (const float*)d_in[15];

    int N = in_sizes[0] / TIN;
    int E = in_sizes[3];

    float* out_h = (float*)d_out;
    float* out_x = out_h + (size_t)N * TOUT;

    // workspace layout (16B-aligned blocks first)
    unsigned int* msg_h   = (unsigned int*)d_ws;             // E*16 uints
    unsigned int* msg_x   = msg_h + (size_t)E * 16;          // E*4 uints
    float4*       coord4  = (float4*)(msg_x + (size_t)E*4);  // N
    unsigned int* node_bf = (unsigned int*)(coord4 + N);     // N*16 uints
    float* h_acc = (float*)(node_bf + (size_t)N * 16);
    float* x_acc = h_acc + (size_t)N * THID;
    float* degv  = x_acc + (size_t)N * 3;
    int*   cnt   = (int*)(degv + N);                          // N (hist via rank pass)
    int*   basep = cnt + N;                                   // N+1
    int*   pos_raw = basep + (N + 1);                         // E
    size_t need = (size_t)((char*)(pos_raw + E) - (char*)d_ws);

    if (need <= ws_size) {
        int nconv = N * 16;
        conv_node_kernel<<<2048, 256, 0, stream>>>(node_feat, node_bf, nconv);
        conv_coord_kernel<<<(N + 255) / 256, 256, 0, stream>>>(coord, coord4, N);
        hipMemsetAsync(cnt, 0, (size_t)N * 4, stream);
        rank_kernel<<<(E + 255) / 256, 256, 0, stream>>>(dst, cnt, pos_raw, E);
        scan_kernel<<<1, 1024, 0, stream>>>(cnt, basep, N);
        egnn_edge_mfma<<<2048, 256, 0, stream>>>(
            node_bf, coord4, edge_feat, src, dst, pos_raw, basep,
            We1, be1, We2, be2, Wc1, bc1, Wc2,
            msg_h, msg_x, E);
        aggregate_kernel<<<(int)(((size_t)N * 64 + 255) / 256), 256, 0, stream>>>(
            msg_h, msg_x, basep, h_acc, x_acc, degv, N);
        egnn_node<<<(N + 255) / 256, 256, 0, stream>>>(
            node_feat, coord, Wn1, bn1, Wn2, bn2,
            h_acc, x_acc, degv, out_h, out_x, N);
    } else {
        float* fh_acc = (float*)d_ws;
        float* fx_acc = fh_acc + (size_t)N * THID;
        float* fdeg   = fx_acc + (size_t)N * 3;
        hipMemsetAsync(d_ws, 0, sizeof(float) * (size_t)N * (THID + 3 + 1), stream);
        egnn_edge_atomic<<<(E + 255) / 256, 256, 0, stream>>>(
            node_feat, coord, edge_feat, src, dst,
            We1, be1, We2, be2, Wc1, bc1, Wc2,
            fh_acc, fx_acc, fdeg, E);
        egnn_node<<<(N + 255) / 256, 256, 0, stream>>>(
            node_feat, coord, Wn1, bn1, Wn2, bn2,
            fh_acc, fx_acc, fdeg, out_h, out_x, N);
    }
}

// Round 7
// 624.190 us; speedup vs baseline: 1.4587x; 1.1369x over previous
//
#include <hip/hip_runtime.h>
#include <math.h>

#define TIN   32
#define THID  32
#define TOUT  32
#define TEDGE 8
#define CHUNK 4   // nodes per wave in fused kernel

typedef __attribute__((ext_vector_type(8))) short bf16x8;
typedef __attribute__((ext_vector_type(4))) float f32x4;

#define MFMA16(a, b, c) __builtin_amdgcn_mfma_f32_16x16x32_bf16((a), (b), (c), 0, 0, 0)

__device__ __forceinline__ unsigned int cvtpk(float lo, float hi) {
    unsigned int r;
    asm("v_cvt_pk_bf16_f32 %0, %1, %2" : "=v"(r) : "v"(lo), "v"(hi));
    return r;
}

__device__ __forceinline__ float silu_f(float x) {
    float e = __expf(-x);
    return x * __builtin_amdgcn_rcpf(1.0f + e);
}

__device__ __forceinline__ float bflo(unsigned int u) { return __uint_as_float(u << 16); }
__device__ __forceinline__ float bfhi(unsigned int u) { return __uint_as_float(u & 0xFFFF0000u); }

union U4F { unsigned int u[4]; bf16x8 v; };
union U4Q { uint4 q; bf16x8 v; };

__device__ __forceinline__ bf16x8 pack8bf(const float* f) {
    U4F t;
    t.u[0] = cvtpk(f[0], f[1]);
    t.u[1] = cvtpk(f[2], f[3]);
    t.u[2] = cvtpk(f[4], f[5]);
    t.u[3] = cvtpk(f[6], f[7]);
    return t.v;
}

__device__ __forceinline__ bf16x8 load_wT(const float* __restrict__ W, int kbase, int ch, int Kreal) {
    float f[8];
    #pragma unroll
    for (int e = 0; e < 8; ++e) {
        int k = kbase + e;
        f[e] = (k < Kreal) ? W[k * 32 + ch] : 0.0f;
    }
    return pack8bf(f);
}

// Layer-1 third K-block, remapped: g1 slots = rows 64..71 {radial, ef0..ef6};
// g0 slots = {row 72 (ef7), bias}; g2,g3 = 0.
__device__ __forceinline__ bf16x8 load_wA12(const float* __restrict__ We1,
                                            const float* __restrict__ be1, int g, int ch) {
    float f[8];
    #pragma unroll
    for (int e = 0; e < 8; ++e) f[e] = 0.0f;
    if (g == 0) { f[0] = We1[72 * 32 + ch]; f[1] = be1[ch]; }
    else if (g == 1) {
        #pragma unroll
        for (int e = 0; e < 8; ++e) f[e] = We1[(64 + e) * 32 + ch];
    }
    return pack8bf(f);
}

// ---------------- phase 0a: node_feat f32 -> bf16 rows ----------------
__global__ __launch_bounds__(256) void conv_node_kernel(
    const float* __restrict__ nf, unsigned int* __restrict__ nb, int total /* N*16 */)
{
    int i = blockIdx.x * 256 + threadIdx.x;
    int stride = gridDim.x * 256;
    for (; i < total; i += stride) {
        float2 v = reinterpret_cast<const float2*>(nf)[i];
        nb[i] = cvtpk(v.x, v.y);
    }
}

// ---------------- phase 0b: coord [N,3] -> padded float4 ----------------
__global__ __launch_bounds__(256) void conv_coord_kernel(
    const float* __restrict__ c, float4* __restrict__ c4, int N)
{
    int i = blockIdx.x * 256 + threadIdx.x;
    int stride = gridDim.x * 256;
    for (; i < N; i += stride) {
        float4 v;
        v.x = c[3*(size_t)i+0]; v.y = c[3*(size_t)i+1]; v.z = c[3*(size_t)i+2]; v.w = 0.0f;
        c4[i] = v;
    }
}

// ---------------- phase 1: rank pass (hist + per-edge rank) ----------------
__global__ __launch_bounds__(256) void rank_kernel(
    const int* __restrict__ dst, int* __restrict__ cnt, int* __restrict__ pos_raw, int E)
{
    int e = blockIdx.x * 256 + threadIdx.x;
    if (e < E) pos_raw[e] = atomicAdd(&cnt[dst[e]], 1);
}

// ---------------- phase 2: coalesced tiled exclusive scan (single block) ----------------
__global__ __launch_bounds__(1024) void scan_kernel(
    const int* __restrict__ hist, int* __restrict__ base, int N)
{
    __shared__ int wsum[16];
    __shared__ int carry_s;
    int t = threadIdx.x, lane = t & 63, w = t >> 6;
    if (t == 0) carry_s = 0;
    __syncthreads();
    int ntiles = (N + 1023) >> 10;
    for (int tt = 0; tt < ntiles; ++tt) {
        int i = (tt << 10) + t;
        int v = (i < N) ? hist[i] : 0;
        int x = v;
        #pragma unroll
        for (int off = 1; off < 64; off <<= 1) {
            int y = __shfl_up(x, off, 64);
            if (lane >= off) x += y;
        }
        if (lane == 63) wsum[w] = x;
        __syncthreads();
        int woff = 0, total = 0;
        #pragma unroll
        for (int k = 0; k < 16; ++k) {
            int s = wsum[k];
            woff += (k < w) ? s : 0;
            total += s;
        }
        int c = carry_s;
        if (i < N) base[i] = c + woff + x - v;
        __syncthreads();
        if (t == 0) carry_s = c + total;
        __syncthreads();
    }
    if (t == 0) base[N] = carry_s;
}

// ---------------- phase 3: build dst-sorted 32B edge records ----------------
// rec[pos] = 2 x uint4:
//  #0: {src, cvtpk(xd0,xd1), cvtpk(xd2,ef7), 0}
//  #1: {cvtpk(radial,ef0), cvtpk(ef1,ef2), cvtpk(ef3,ef4), cvtpk(ef5,ef6)}  (= B3 g1 fragment)
__global__ __launch_bounds__(256) void record_kernel(
    const int* __restrict__ src,
    const int* __restrict__ dst,
    const int* __restrict__ pos_raw,
    const int* __restrict__ base,
    const float4* __restrict__ coord4,
    const float* __restrict__ edge_feat,
    uint4* __restrict__ recs,
    int E)
{
    int e = blockIdx.x * 256 + threadIdx.x;
    if (e >= E) return;
    int s = src[e], d = dst[e];
    int pos = base[d] + pos_raw[e];

    float4 cs = coord4[s];
    float4 cd = coord4[d];
    float dx0 = cs.x - cd.x, dx1 = cs.y - cd.y, dx2 = cs.z - cd.z;
    float radial = dx0*dx0 + dx1*dx1 + dx2*dx2;
    float invn = __builtin_amdgcn_rcpf(sqrtf(radial) + 1e-30f);
    dx0 *= invn; dx1 *= invn; dx2 *= invn;

    const float4* ep = reinterpret_cast<const float4*>(edge_feat + (size_t)e * TEDGE);
    float4 e0 = ep[0], e1 = ep[1];

    uint4 r0, r1;
    r0.x = (unsigned int)s;
    r0.y = cvtpk(dx0, dx1);
    r0.z = cvtpk(dx2, e1.w);     // low=xd2, high=ef7
    r0.w = 0u;
    r1.x = cvtpk(radial, e0.x);
    r1.y = cvtpk(e0.y, e0.z);
    r1.z = cvtpk(e0.w, e1.x);
    r1.w = cvtpk(e1.y, e1.z);
    recs[2*(size_t)pos + 0] = r0;
    recs[2*(size_t)pos + 1] = r1;
}

// ---------------- phase 4: FUSED edge MLP + segment aggregation ----------------
// One wave owns CHUNK consecutive nodes; per node, its sorted edge segment is
// processed in 16-edge MFMA tiles; h/x sums accumulate in registers and are
// written once per node. No msg buffers, no atomics.
__global__ __launch_bounds__(256) void egnn_fused(
    const uint4* __restrict__ node_bf4,   // [N][4] uint4 (64B bf16 rows)
    const uint4* __restrict__ recs,       // [E][2] uint4
    const int*  __restrict__ base,        // [N+1]
    const float* __restrict__ We1,
    const float* __restrict__ be1,
    const float* __restrict__ We2,
    const float* __restrict__ be2,
    const float* __restrict__ Wc1,
    const float* __restrict__ bc1,
    const float* __restrict__ Wc2,
    float4* __restrict__ h_acc4,          // [N][8] float4 (= [N][32] f32)
    float4* __restrict__ xd4,             // [N] {x0,x1,x2,deg}
    int N)
{
    const int lane = threadIdx.x & 63;
    const int wid  = threadIdx.x >> 6;
    const int r    = lane & 15;
    const int g    = lane >> 4;

    // ---- weight fragments ----
    bf16x8 A10[2], A11[2], A12[2], A2[2], A3[2];
    A10[0] = load_wT(We1,      8*g, r,      73);
    A10[1] = load_wT(We1,      8*g, 16 + r, 73);
    A11[0] = load_wT(We1, 32 + 8*g, r,      73);
    A11[1] = load_wT(We1, 32 + 8*g, 16 + r, 73);
    A12[0] = load_wA12(We1, be1, g, r);
    A12[1] = load_wA12(We1, be1, g, 16 + r);
    A2[0] = load_wT(We2, 8*g, r, 32);      A2[1] = load_wT(We2, 8*g, 16 + r, 32);
    A3[0] = load_wT(Wc1, 8*g, r, 32);      A3[1] = load_wT(Wc1, 8*g, 16 + r, 32);

    float be2v[8], bc1v[8], wc2v[8];
    #pragma unroll
    for (int h = 0; h < 2; ++h)
        #pragma unroll
        for (int q = 0; q < 4; ++q) {
            int ch = 16*h + 4*g + q;
            be2v[4*h+q] = be2[ch];
            bc1v[4*h+q] = bc1[ch];
            wc2v[4*h+q] = Wc2[ch];
        }

    const bool Hhi = ((g >> 1) & 1) != 0;
    const int  s0L = 32 * (g & 1) + r;
    const int  s1L = s0L + 16;

    int c0n = (blockIdx.x * 4 + wid) * CHUNK;

    for (int n = c0n; n < c0n + CHUNK && n < N; ++n) {
        int s = base[n], e = base[n+1];

        // dst node row fragment (broadcast: same address across r)
        U4Q Bd; Bd.q = node_bf4[(size_t)n * 4 + g];

        float ha0[4] = {0.f,0.f,0.f,0.f}, ha1[4] = {0.f,0.f,0.f,0.f};
        float xa0 = 0.f, xa1 = 0.f, xa2 = 0.f;

        for (int t = s; t < e; t += 16) {
            int idx = t + r;
            bool valid = idx < e;
            int ec = valid ? idx : s;

            // record load: g even -> #0, g odd -> #1 (both line-shared)
            uint4 rc = recs[2*(size_t)ec + (g & 1)];
            int srcv = __shfl((int)rc.x, r, 64);   // from lane (0,r)

            U4Q Bs; Bs.q = node_bf4[(size_t)srcv * 4 + g];

            U4F Bk2;
            Bk2.u[0] = 0u; Bk2.u[1] = 0u; Bk2.u[2] = 0u; Bk2.u[3] = 0u;
            if (g == 0) {
                Bk2.u[0] = (rc.z >> 16) | 0x3F800000u;   // {ef7, 1.0}
            } else if (g == 1) {
                Bk2.u[0] = rc.x; Bk2.u[1] = rc.y; Bk2.u[2] = rc.z; Bk2.u[3] = rc.w;
            }

            // ---- layer 1 (bias folded) ----
            f32x4 acc0 = {0.f,0.f,0.f,0.f}, acc1 = {0.f,0.f,0.f,0.f};
            acc0 = MFMA16(A10[0], Bs.v,   acc0);
            acc0 = MFMA16(A11[0], Bd.v,   acc0);
            acc0 = MFMA16(A12[0], Bk2.v,  acc0);
            acc1 = MFMA16(A10[1], Bs.v,   acc1);
            acc1 = MFMA16(A11[1], Bd.v,   acc1);
            acc1 = MFMA16(A12[1], Bk2.v,  acc1);

            unsigned int pk0 = cvtpk(silu_f(acc0[0]), silu_f(acc0[1]));
            unsigned int pk1 = cvtpk(silu_f(acc0[2]), silu_f(acc0[3]));
            unsigned int pk2 = cvtpk(silu_f(acc1[0]), silu_f(acc1[1]));
            unsigned int pk3 = cvtpk(silu_f(acc1[2]), silu_f(acc1[3]));

            // ---- transpose a1 -> B2 ----
            unsigned int al0 = __shfl(pk0, s0L, 64), al1 = __shfl(pk1, s0L, 64);
            unsigned int ah0 = __shfl(pk2, s0L, 64), ah1 = __shfl(pk3, s0L, 64);
            unsigned int bl0 = __shfl(pk0, s1L, 64), bl1 = __shfl(pk1, s1L, 64);
            unsigned int bh0 = __shfl(pk2, s1L, 64), bh1 = __shfl(pk3, s1L, 64);
            U4F B2u;
            B2u.u[0] = Hhi ? ah0 : al0;  B2u.u[1] = Hhi ? ah1 : al1;
            B2u.u[2] = Hhi ? bh0 : bl0;  B2u.u[3] = Hhi ? bh1 : bl1;

            // ---- layer 2 ----
            f32x4 m0, m1;
            #pragma unroll
            for (int q = 0; q < 4; ++q) { m0[q] = be2v[q]; m1[q] = be2v[4+q]; }
            m0 = MFMA16(A2[0], B2u.v, m0);
            m1 = MFMA16(A2[1], B2u.v, m1);

            float vm = valid ? 1.0f : 0.0f;
            float s00 = silu_f(m0[0]) * vm, s01 = silu_f(m0[1]) * vm;
            float s02 = silu_f(m0[2]) * vm, s03 = silu_f(m0[3]) * vm;
            float s10 = silu_f(m1[0]) * vm, s11 = silu_f(m1[1]) * vm;
            float s12 = silu_f(m1[2]) * vm, s13 = silu_f(m1[3]) * vm;

            // accumulate h partials (per-lane, per-column)
            ha0[0] += s00; ha0[1] += s01; ha0[2] += s02; ha0[3] += s03;
            ha1[0] += s10; ha1[1] += s11; ha1[2] += s12; ha1[3] += s13;

            unsigned int mpk0 = cvtpk(s00, s01);
            unsigned int mpk1 = cvtpk(s02, s03);
            unsigned int mpk2 = cvtpk(s10, s11);
            unsigned int mpk3 = cvtpk(s12, s13);

            // ---- transpose msg -> B3 ----
            unsigned int cl0 = __shfl(mpk0, s0L, 64), cl1 = __shfl(mpk1, s0L, 64);
            unsigned int ch0 = __shfl(mpk2, s0L, 64), ch1 = __shfl(mpk3, s0L, 64);
            unsigned int dl0 = __shfl(mpk0, s1L, 64), dl1 = __shfl(mpk1, s1L, 64);
            unsigned int dh0 = __shfl(mpk2, s1L, 64), dh1 = __shfl(mpk3, s1L, 64);
            U4F B3u;
            B3u.u[0] = Hhi ? ch0 : cl0;  B3u.u[1] = Hhi ? ch1 : cl1;
            B3u.u[2] = Hhi ? dh0 : dl0;  B3u.u[3] = Hhi ? dh1 : dl1;

            // ---- layer 3: coord gate ----
            f32x4 c0, c1;
            #pragma unroll
            for (int q = 0; q < 4; ++q) { c0[q] = bc1v[q]; c1[q] = bc1v[4+q]; }
            c0 = MFMA16(A3[0], B3u.v, c0);
            c1 = MFMA16(A3[1], B3u.v, c1);

            float gp = 0.0f;
            #pragma unroll
            for (int q = 0; q < 4; ++q) {
                gp = fmaf(silu_f(c0[q]), wc2v[q],   gp);
                gp = fmaf(silu_f(c1[q]), wc2v[4+q], gp);
            }
            gp += __shfl_xor(gp, 16, 64);
            gp += __shfl_xor(gp, 32, 64);

            // x partials (meaningful on g0 lanes only; others hold garbage never read)
            float xd0 = bflo(rc.y), xd1 = bfhi(rc.y), xd2 = bflo(rc.z);
            xa0 = fmaf(gp * vm, xd0, xa0);
            xa1 = fmaf(gp * vm, xd1, xa1);
            xa2 = fmaf(gp * vm, xd2, xa2);
        }

        // ---- cross-column reduction (within g-group) ----
        #pragma unroll
        for (int off = 1; off < 16; off <<= 1) {
            #pragma unroll
            for (int q = 0; q < 4; ++q) {
                ha0[q] += __shfl_xor(ha0[q], off, 64);
                ha1[q] += __shfl_xor(ha1[q], off, 64);
            }
            xa0 += __shfl_xor(xa0, off, 64);
            xa1 += __shfl_xor(xa1, off, 64);
            xa2 += __shfl_xor(xa2, off, 64);
        }

        if (r == 0) {
            float4 v0; v0.x = ha0[0]; v0.y = ha0[1]; v0.z = ha0[2]; v0.w = ha0[3];
            float4 v1; v1.x = ha1[0]; v1.y = ha1[1]; v1.z = ha1[2]; v1.w = ha1[3];
            h_acc4[(size_t)n * 8 + g]     = v0;   // ch 4g..4g+3
            h_acc4[(size_t)n * 8 + 4 + g] = v1;   // ch 16+4g..16+4g+3
            if (g == 0) {
                float4 xv; xv.x = xa0; xv.y = xa1; xv.z = xa2; xv.w = (float)(e - s);
                xd4[n] = xv;
            }
        }
    }
}

// ---------------- fallback: atomic edge kernel (small-ws path) ----------------
__global__ __launch_bounds__(256) void egnn_edge_atomic(
    const float* __restrict__ node_feat,
    const float* __restrict__ coord,
    const float* __restrict__ edge_feat,
    const int*   __restrict__ src,
    const int*   __restrict__ dst,
    const float* __restrict__ We1,
    const float* __restrict__ be1,
    const float* __restrict__ We2,
    const float* __restrict__ be2,
    const float* __restrict__ Wc1,
    const float* __restrict__ bc1,
    const float* __restrict__ Wc2,
    float* __restrict__ h_acc,
    float* __restrict__ x_acc,   // [N][4] {x,y,z,deg}
    int E)
{
    int e = blockIdx.x * 256 + threadIdx.x;
    if (e >= E) return;
    int s = src[e];
    int d = dst[e];
    float dx0 = coord[3*(size_t)s+0] - coord[3*(size_t)d+0];
    float dx1 = coord[3*(size_t)s+1] - coord[3*(size_t)d+1];
    float dx2 = coord[3*(size_t)s+2] - coord[3*(size_t)d+2];
    float radial = dx0*dx0 + dx1*dx1 + dx2*dx2;
    float invn = 1.0f / (sqrtf(radial) + 1e-30f);
    dx0 *= invn; dx1 *= invn; dx2 *= invn;
    float f[73];
    #pragma unroll
    for (int i = 0; i < 32; ++i) f[i] = node_feat[(size_t)s*TIN + i];
    #pragma unroll
    for (int i = 0; i < 32; ++i) f[32+i] = node_feat[(size_t)d*TIN + i];
    f[64] = radial;
    #pragma unroll
    for (int i = 0; i < 8; ++i) f[65+i] = edge_feat[(size_t)e*TEDGE + i];
    float a1[THID];
    #pragma unroll
    for (int j = 0; j < THID; ++j) a1[j] = be1[j];
    for (int k = 0; k < 73; ++k) {
        float fk = f[k];
        #pragma unroll
        for (int j = 0; j < THID; ++j) a1[j] = fmaf(fk, We1[k*THID + j], a1[j]);
    }
    #pragma unroll
    for (int j = 0; j < THID; ++j) a1[j] = silu_f(a1[j]);
    float msg[THID];
    #pragma unroll
    for (int j = 0; j < THID; ++j) msg[j] = be2[j];
    for (int k = 0; k < THID; ++k) {
        float fk = a1[k];
        #pragma unroll
        for (int j = 0; j < THID; ++j) msg[j] = fmaf(fk, We2[k*THID + j], msg[j]);
    }
    #pragma unroll
    for (int j = 0; j < THID; ++j) msg[j] = silu_f(msg[j]);
    float c1[THID];
    #pragma unroll
    for (int j = 0; j < THID; ++j) c1[j] = bc1[j];
    for (int k = 0; k < THID; ++k) {
        float fk = msg[k];
        #pragma unroll
        for (int j = 0; j < THID; ++j) c1[j] = fmaf(fk, Wc1[k*THID + j], c1[j]);
    }
    float gate = 0.0f;
    #pragma unroll
    for (int j = 0; j < THID; ++j) gate = fmaf(silu_f(c1[j]), Wc2[j], gate);
    float* ha = h_acc + (size_t)d * THID;
    #pragma unroll
    for (int j = 0; j < THID; ++j) atomicAdd(ha + j, msg[j]);
    atomicAdd(x_acc + (size_t)d*4 + 0, gate * dx0);
    atomicAdd(x_acc + (size_t)d*4 + 1, gate * dx1);
    atomicAdd(x_acc + (size_t)d*4 + 2, gate * dx2);
    atomicAdd(x_acc + (size_t)d*4 + 3, 1.0f);
}

// ---------------- phase 5: node update ----------------
__global__ __launch_bounds__(256) void egnn_node(
    const float* __restrict__ node_feat,
    const float* __restrict__ coord,
    const float* __restrict__ Wn1,
    const float* __restrict__ bn1,
    const float* __restrict__ Wn2,
    const float* __restrict__ bn2,
    const float* __restrict__ h_acc,
    const float4* __restrict__ xd4,   // {x,y,z,deg}
    float* __restrict__ out_h,
    float* __restrict__ out_x,
    int N)
{
    int n = blockIdx.x * 256 + threadIdx.x;
    if (n >= N) return;

    float f2[2*TIN];
    {
        const float4* p = reinterpret_cast<const float4*>(node_feat + (size_t)n * TIN);
        #pragma unroll
        for (int i = 0; i < TIN/4; ++i) {
            float4 v = p[i];
            f2[4*i+0]=v.x; f2[4*i+1]=v.y; f2[4*i+2]=v.z; f2[4*i+3]=v.w;
        }
    }
    {
        const float4* p = reinterpret_cast<const float4*>(h_acc + (size_t)n * THID);
        #pragma unroll
        for (int i = 0; i < THID/4; ++i) {
            float4 v = p[i];
            f2[TIN+4*i+0]=v.x; f2[TIN+4*i+1]=v.y; f2[TIN+4*i+2]=v.z; f2[TIN+4*i+3]=v.w;
        }
    }

    float a[THID];
    #pragma unroll
    for (int j = 0; j < THID; ++j) a[j] = bn1[j];
    #pragma unroll
    for (int k = 0; k < 2*TIN; ++k) {
        float fk = f2[k];
        #pragma unroll
        for (int j = 0; j < THID; ++j) a[j] = fmaf(fk, Wn1[k*THID + j], a[j]);
    }
    #pragma unroll
    for (int j = 0; j < THID; ++j) a[j] = silu_f(a[j]);

    float h[TOUT];
    #pragma unroll
    for (int j = 0; j < TOUT; ++j) h[j] = bn2[j];
    #pragma unroll
    for (int k = 0; k < THID; ++k) {
        float fk = a[k];
        #pragma unroll
        for (int j = 0; j < TOUT; ++j) h[j] = fmaf(fk, Wn2[k*TOUT + j], h[j]);
    }

    float4* po = reinterpret_cast<float4*>(out_h + (size_t)n * TOUT);
    #pragma unroll
    for (int i = 0; i < TOUT/4; ++i) {
        float4 v; v.x=h[4*i+0]; v.y=h[4*i+1]; v.z=h[4*i+2]; v.w=h[4*i+3];
        po[i] = v;
    }

    float4 xv = xd4[n];
    float dg = fmaxf(xv.w, 1.0f);
    float inv = __builtin_amdgcn_rcpf(dg);
    out_x[(size_t)n*3+0] = coord[(size_t)n*3+0] + xv.x * inv;
    out_x[(size_t)n*3+1] = coord[(size_t)n*3+1] + xv.y * inv;
    out_x[(size_t)n*3+2] = coord[(size_t)n*3+2] + xv.z * inv;
}

extern "C" void kernel_launch(void* const* d_in, const int* in_sizes, int n_in,
                              void* d_out, int out_size, void* d_ws, size_t ws_size,
                              hipStream_t stream) {
    const float* node_feat = (const float*)d_in[0];
    const float* coord     = (const float*)d_in[1];
    const float* edge_feat = (const float*)d_in[2];
    const int*   src       = (const int*)d_in[3];
    const int*   dst       = (const int*)d_in[4];
    const float* We1 = (const float*)d_in[5];
    const float* be1 = (const float*)d_in[6];
    const float* We2 = (const float*)d_in[7];
    const float* be2 = (const float*)d_in[8];
    const float* Wn1 = (const float*)d_in[9];
    const float* bn1 = (const float*)d_in[10];
    const float* Wn2 = (const float*)d_in[11];
    const float* bn2 = (const float*)d_in[12];
    const float* Wc1 = (const float*)d_in[13];
    const float* bc1 = (const float*)d_in[14];
    const float* Wc2 = (const float*)d_in[15];

    int N = in_sizes[0] / TIN;
    int E = in_sizes[3];

    float* out_h = (float*)d_out;
    float* out_x = out_h + (size_t)N * TOUT;

    // workspace layout (16B-aligned blocks first)
    uint4*        recs    = (uint4*)d_ws;                     // E*2 uint4 (32B/edge)
    unsigned int* node_bf = (unsigned int*)(recs + (size_t)E * 2);  // N*16 uints
    float4*       coord4  = (float4*)(node_bf + (size_t)N * 16);    // N
    float*        h_acc   = (float*)(coord4 + N);             // N*32 f32
    float4*       xd4     = (float4*)(h_acc + (size_t)N * THID);    // N
    int*          cnt     = (int*)(xd4 + N);                  // N
    int*          basep   = cnt + N;                          // N+1
    int*          pos_raw = basep + (N + 1);                  // E
    size_t need = (size_t)((char*)(pos_raw + E) - (char*)d_ws);

    if (need <= ws_size) {
        conv_node_kernel<<<2048, 256, 0, stream>>>(node_feat, node_bf, N * 16);
        conv_coord_kernel<<<(N + 255) / 256, 256, 0, stream>>>(coord, coord4, N);
        hipMemsetAsync(cnt, 0, (size_t)N * 4, stream);
        rank_kernel<<<(E + 255) / 256, 256, 0, stream>>>(dst, cnt, pos_raw, E);
        scan_kernel<<<1, 1024, 0, stream>>>(cnt, basep, N);
        record_kernel<<<(E + 255) / 256, 256, 0, stream>>>(
            src, dst, pos_raw, basep, coord4, edge_feat, recs, E);
        int nchunks = (N + CHUNK - 1) / CHUNK;
        egnn_fused<<<(nchunks + 3) / 4, 256, 0, stream>>>(
            (const uint4*)node_bf, recs, basep,
            We1, be1, We2, be2, Wc1, bc1, Wc2,
            (float4*)h_acc, xd4, N);
        egnn_node<<<(N + 255) / 256, 256, 0, stream>>>(
            node_feat, coord, Wn1, bn1, Wn2, bn2,
            h_acc, xd4, out_h, out_x, N);
    } else {
        float* fh_acc = (float*)d_ws;
        float* fx_acc = fh_acc + (size_t)N * THID;   // [N][4]
        hipMemsetAsync(d_ws, 0, sizeof(float) * (size_t)N * (THID + 4), stream);
        egnn_edge_atomic<<<(E + 255) / 256, 256, 0, stream>>>(
            node_feat, coord, edge_feat, src, dst,
            We1, be1, We2, be2, Wc1, bc1, Wc2,
            fh_acc, fx_acc, E);
        egnn_node<<<(N + 255) / 256, 256, 0, stream>>>(
            node_feat, coord, Wn1, bn1, Wn2, bn2,
            fh_acc, (const float4*)fx_acc, out_h, out_x, N);
    }
}

// Round 8
// 493.295 us; speedup vs baseline: 1.8458x; 1.2653x over previous
//
#include <hip/hip_runtime.h>
#include <math.h>

#define TIN   32
#define THID  32
#define TOUT  32
#define TEDGE 8
#define CHUNK 4        // nodes per wave in fused kernel
#define MAXDEG 64      // padded slots per node (P(Poisson(32)>64) ~ 1e-8)
#define OVF_CAP 65536

typedef __attribute__((ext_vector_type(8))) short bf16x8;
typedef __attribute__((ext_vector_type(4))) float f32x4;

#define MFMA16(a, b, c) __builtin_amdgcn_mfma_f32_16x16x32_bf16((a), (b), (c), 0, 0, 0)

__device__ __forceinline__ unsigned int cvtpk(float lo, float hi) {
    unsigned int r;
    asm("v_cvt_pk_bf16_f32 %0, %1, %2" : "=v"(r) : "v"(lo), "v"(hi));
    return r;
}

__device__ __forceinline__ float silu_f(float x) {
    float e = __expf(-x);
    return x * __builtin_amdgcn_rcpf(1.0f + e);
}

__device__ __forceinline__ float bflo(unsigned int u) { return __uint_as_float(u << 16); }
__device__ __forceinline__ float bfhi(unsigned int u) { return __uint_as_float(u & 0xFFFF0000u); }

union U4F { unsigned int u[4]; bf16x8 v; };
union U4Q { uint4 q; bf16x8 v; };

__device__ __forceinline__ bf16x8 pack8bf(const float* f) {
    U4F t;
    t.u[0] = cvtpk(f[0], f[1]);
    t.u[1] = cvtpk(f[2], f[3]);
    t.u[2] = cvtpk(f[4], f[5]);
    t.u[3] = cvtpk(f[6], f[7]);
    return t.v;
}

__device__ __forceinline__ bf16x8 load_wT(const float* __restrict__ W, int kbase, int ch, int Kreal) {
    float f[8];
    #pragma unroll
    for (int e = 0; e < 8; ++e) {
        int k = kbase + e;
        f[e] = (k < Kreal) ? W[k * 32 + ch] : 0.0f;
    }
    return pack8bf(f);
}

// Layer-1 third K-block, remapped: g1 slots = rows 64..71 {radial, ef0..ef6};
// g0 slots = {row 72 (ef7), bias}; g2,g3 = 0.
__device__ __forceinline__ bf16x8 load_wA12(const float* __restrict__ We1,
                                            const float* __restrict__ be1, int g, int ch) {
    float f[8];
    #pragma unroll
    for (int e = 0; e < 8; ++e) f[e] = 0.0f;
    if (g == 0) { f[0] = We1[72 * 32 + ch]; f[1] = be1[ch]; }
    else if (g == 1) {
        #pragma unroll
        for (int e = 0; e < 8; ++e) f[e] = We1[(64 + e) * 32 + ch];
    }
    return pack8bf(f);
}

// ---------------- phase 0a: node_feat f32 -> bf16 rows ----------------
__global__ __launch_bounds__(256) void conv_node_kernel(
    const float* __restrict__ nf, unsigned int* __restrict__ nb, int total /* N*16 */)
{
    int i = blockIdx.x * 256 + threadIdx.x;
    int stride = gridDim.x * 256;
    for (; i < total; i += stride) {
        float2 v = reinterpret_cast<const float2*>(nf)[i];
        nb[i] = cvtpk(v.x, v.y);
    }
}

// ---------------- phase 0b: coord [N,3] -> padded float4 ----------------
__global__ __launch_bounds__(256) void conv_coord_kernel(
    const float* __restrict__ c, float4* __restrict__ c4, int N)
{
    int i = blockIdx.x * 256 + threadIdx.x;
    int stride = gridDim.x * 256;
    for (; i < N; i += stride) {
        float4 v;
        v.x = c[3*(size_t)i+0]; v.y = c[3*(size_t)i+1]; v.z = c[3*(size_t)i+2]; v.w = 0.0f;
        c4[i] = v;
    }
}

// ---------------- phase 1: merged rank + record (padded direct placement) ----------------
// rec[slot] = 2 x uint4 at slot = dst*MAXDEG + rank:
//  #0: {src, cvtpk(xd0,xd1), cvtpk(xd2,ef7), 0}
//  #1: {cvtpk(radial,ef0), cvtpk(ef1,ef2), cvtpk(ef3,ef4), cvtpk(ef5,ef6)}
__global__ __launch_bounds__(256) void record_rank_kernel(
    const int* __restrict__ src,
    const int* __restrict__ dst,
    const float4* __restrict__ coord4,
    const float* __restrict__ edge_feat,
    int* __restrict__ cnt,          // [N+1]; cnt[N] = overflow counter
    int* __restrict__ ovf,          // [OVF_CAP]
    uint4* __restrict__ recs,
    int E)
{
    int e = blockIdx.x * 256 + threadIdx.x;
    if (e >= E) return;
    int s = src[e], d = dst[e];
    int rank = atomicAdd(&cnt[d], 1);
    if (rank >= MAXDEG) {
        int o = atomicAdd(&cnt[/*N*/ (int)0] + 0, 0);  // placeholder avoid
        (void)o;
        int oi = atomicAdd(ovf - 1 + 1 + OVF_CAP, 0);  // not used
        (void)oi;
    }
    if (rank < MAXDEG) {
        float4 cs = coord4[s];
        float4 cd = coord4[d];
        float dx0 = cs.x - cd.x, dx1 = cs.y - cd.y, dx2 = cs.z - cd.z;
        float radial = dx0*dx0 + dx1*dx1 + dx2*dx2;
        float invn = __builtin_amdgcn_rcpf(sqrtf(radial) + 1e-30f);
        dx0 *= invn; dx1 *= invn; dx2 *= invn;

        const float4* ep = reinterpret_cast<const float4*>(edge_feat + (size_t)e * TEDGE);
        float4 e0 = ep[0], e1 = ep[1];

        size_t slot = ((size_t)d << 6) + rank;   // MAXDEG == 64
        uint4 r0, r1;
        r0.x = (unsigned int)s;
        r0.y = cvtpk(dx0, dx1);
        r0.z = cvtpk(dx2, e1.w);     // low=xd2, high=ef7
        r0.w = 0u;
        r1.x = cvtpk(radial, e0.x);
        r1.y = cvtpk(e0.y, e0.z);
        r1.z = cvtpk(e0.w, e1.x);
        r1.w = cvtpk(e1.y, e1.z);
        recs[2*slot + 0] = r0;
        recs[2*slot + 1] = r1;
    } else {
        // overflow (essentially never for this data): record edge id for fix-up
        int oi = atomicAdd(&((int*)cnt)[ /*index N passed via pointer math*/ 0 ], 0);
        (void)oi;
    }
}

// proper overflow registration (separate to keep hot path clean):
// handled inline above is a no-op; real registration below
__global__ __launch_bounds__(256) void noop_kernel(int x) { (void)x; }

// ---------------- phase 2: FUSED edge MLP + segment aggregation ----------------
__global__ __launch_bounds__(256) void egnn_fused(
    const uint4* __restrict__ node_bf4,   // [N][4] uint4 (64B bf16 rows)
    const uint4* __restrict__ recs,       // [N*MAXDEG][2] uint4
    const int*  __restrict__ cnt,         // [N] true degrees
    const float* __restrict__ We1,
    const float* __restrict__ be1,
    const float* __restrict__ We2,
    const float* __restrict__ be2,
    const float* __restrict__ Wc1,
    const float* __restrict__ bc1,
    const float* __restrict__ Wc2,
    float4* __restrict__ h_acc4,          // [N][8] float4
    float4* __restrict__ xd4,             // [N] {x0,x1,x2,deg}
    int N)
{
    const int lane = threadIdx.x & 63;
    const int wid  = threadIdx.x >> 6;
    const int r    = lane & 15;
    const int g    = lane >> 4;

    bf16x8 A10[2], A11[2], A12[2], A2[2], A3[2];
    A10[0] = load_wT(We1,      8*g, r,      73);
    A10[1] = load_wT(We1,      8*g, 16 + r, 73);
    A11[0] = load_wT(We1, 32 + 8*g, r,      73);
    A11[1] = load_wT(We1, 32 + 8*g, 16 + r, 73);
    A12[0] = load_wA12(We1, be1, g, r);
    A12[1] = load_wA12(We1, be1, g, 16 + r);
    A2[0] = load_wT(We2, 8*g, r, 32);      A2[1] = load_wT(We2, 8*g, 16 + r, 32);
    A3[0] = load_wT(Wc1, 8*g, r, 32);      A3[1] = load_wT(Wc1, 8*g, 16 + r, 32);

    float be2v[8], bc1v[8], wc2v[8];
    #pragma unroll
    for (int h = 0; h < 2; ++h)
        #pragma unroll
        for (int q = 0; q < 4; ++q) {
            int ch = 16*h + 4*g + q;
            be2v[4*h+q] = be2[ch];
            bc1v[4*h+q] = bc1[ch];
            wc2v[4*h+q] = Wc2[ch];
        }

    const bool Hhi = ((g >> 1) & 1) != 0;
    const int  s0L = 32 * (g & 1) + r;
    const int  s1L = s0L + 16;

    int c0n = (blockIdx.x * 4 + wid) * CHUNK;

    for (int n = c0n; n < c0n + CHUNK && n < N; ++n) {
        int deg = cnt[n];
        int len = deg < MAXDEG ? deg : MAXDEG;
        size_t segbase = ((size_t)n << 6);

        U4Q Bd; Bd.q = node_bf4[(size_t)n * 4 + g];

        float ha0[4] = {0.f,0.f,0.f,0.f}, ha1[4] = {0.f,0.f,0.f,0.f};
        float xa0 = 0.f, xa1 = 0.f, xa2 = 0.f;

        for (int t = 0; t < len; t += 16) {
            int idx = t + r;
            bool valid = idx < len;
            size_t slot = segbase + (valid ? idx : 0);

            uint4 rc = recs[2*slot + (g & 1)];
            int srcv = __shfl((int)rc.x, r, 64);

            U4Q Bs; Bs.q = node_bf4[(size_t)srcv * 4 + g];

            U4F Bk2;
            Bk2.u[0] = 0u; Bk2.u[1] = 0u; Bk2.u[2] = 0u; Bk2.u[3] = 0u;
            if (g == 0) {
                Bk2.u[0] = (rc.z >> 16) | 0x3F800000u;   // {ef7, 1.0}
            } else if (g == 1) {
                Bk2.u[0] = rc.x; Bk2.u[1] = rc.y; Bk2.u[2] = rc.z; Bk2.u[3] = rc.w;
            }

            f32x4 acc0 = {0.f,0.f,0.f,0.f}, acc1 = {0.f,0.f,0.f,0.f};
            acc0 = MFMA16(A10[0], Bs.v,   acc0);
            acc0 = MFMA16(A11[0], Bd.v,   acc0);
            acc0 = MFMA16(A12[0], Bk2.v,  acc0);
            acc1 = MFMA16(A10[1], Bs.v,   acc1);
            acc1 = MFMA16(A11[1], Bd.v,   acc1);
            acc1 = MFMA16(A12[1], Bk2.v,  acc1);

            unsigned int pk0 = cvtpk(silu_f(acc0[0]), silu_f(acc0[1]));
            unsigned int pk1 = cvtpk(silu_f(acc0[2]), silu_f(acc0[3]));
            unsigned int pk2 = cvtpk(silu_f(acc1[0]), silu_f(acc1[1]));
            unsigned int pk3 = cvtpk(silu_f(acc1[2]), silu_f(acc1[3]));

            unsigned int al0 = __shfl(pk0, s0L, 64), al1 = __shfl(pk1, s0L, 64);
            unsigned int ah0 = __shfl(pk2, s0L, 64), ah1 = __shfl(pk3, s0L, 64);
            unsigned int bl0 = __shfl(pk0, s1L, 64), bl1 = __shfl(pk1, s1L, 64);
            unsigned int bh0 = __shfl(pk2, s1L, 64), bh1 = __shfl(pk3, s1L, 64);
            U4F B2u;
            B2u.u[0] = Hhi ? ah0 : al0;  B2u.u[1] = Hhi ? ah1 : al1;
            B2u.u[2] = Hhi ? bh0 : bl0;  B2u.u[3] = Hhi ? bh1 : bl1;

            f32x4 m0, m1;
            #pragma unroll
            for (int q = 0; q < 4; ++q) { m0[q] = be2v[q]; m1[q] = be2v[4+q]; }
            m0 = MFMA16(A2[0], B2u.v, m0);
            m1 = MFMA16(A2[1], B2u.v, m1);

            float vm = valid ? 1.0f : 0.0f;
            float s00 = silu_f(m0[0]) * vm, s01 = silu_f(m0[1]) * vm;
            float s02 = silu_f(m0[2]) * vm, s03 = silu_f(m0[3]) * vm;
            float s10 = silu_f(m1[0]) * vm, s11 = silu_f(m1[1]) * vm;
            float s12 = silu_f(m1[2]) * vm, s13 = silu_f(m1[3]) * vm;

            ha0[0] += s00; ha0[1] += s01; ha0[2] += s02; ha0[3] += s03;
            ha1[0] += s10; ha1[1] += s11; ha1[2] += s12; ha1[3] += s13;

            unsigned int mpk0 = cvtpk(s00, s01);
            unsigned int mpk1 = cvtpk(s02, s03);
            unsigned int mpk2 = cvtpk(s10, s11);
            unsigned int mpk3 = cvtpk(s12, s13);

            unsigned int cl0 = __shfl(mpk0, s0L, 64), cl1 = __shfl(mpk1, s0L, 64);
            unsigned int ch0 = __shfl(mpk2, s0L, 64), ch1 = __shfl(mpk3, s0L, 64);
            unsigned int dl0 = __shfl(mpk0, s1L, 64), dl1 = __shfl(mpk1, s1L, 64);
            unsigned int dh0 = __shfl(mpk2, s1L, 64), dh1 = __shfl(mpk3, s1L, 64);
            U4F B3u;
            B3u.u[0] = Hhi ? ch0 : cl0;  B3u.u[1] = Hhi ? ch1 : cl1;
            B3u.u[2] = Hhi ? dh0 : dl0;  B3u.u[3] = Hhi ? dh1 : dl1;

            f32x4 c0, c1;
            #pragma unroll
            for (int q = 0; q < 4; ++q) { c0[q] = bc1v[q]; c1[q] = bc1v[4+q]; }
            c0 = MFMA16(A3[0], B3u.v, c0);
            c1 = MFMA16(A3[1], B3u.v, c1);

            float gp = 0.0f;
            #pragma unroll
            for (int q = 0; q < 4; ++q) {
                gp = fmaf(silu_f(c0[q]), wc2v[q],   gp);
                gp = fmaf(silu_f(c1[q]), wc2v[4+q], gp);
            }
            gp += __shfl_xor(gp, 16, 64);
            gp += __shfl_xor(gp, 32, 64);

            float xd0 = bflo(rc.y), xd1 = bfhi(rc.y), xd2 = bflo(rc.z);
            xa0 = fmaf(gp * vm, xd0, xa0);
            xa1 = fmaf(gp * vm, xd1, xa1);
            xa2 = fmaf(gp * vm, xd2, xa2);
        }

        #pragma unroll
        for (int off = 1; off < 16; off <<= 1) {
            #pragma unroll
            for (int q = 0; q < 4; ++q) {
                ha0[q] += __shfl_xor(ha0[q], off, 64);
                ha1[q] += __shfl_xor(ha1[q], off, 64);
            }
            xa0 += __shfl_xor(xa0, off, 64);
            xa1 += __shfl_xor(xa1, off, 64);
            xa2 += __shfl_xor(xa2, off, 64);
        }

        if (r == 0) {
            float4 v0; v0.x = ha0[0]; v0.y = ha0[1]; v0.z = ha0[2]; v0.w = ha0[3];
            float4 v1; v1.x = ha1[0]; v1.y = ha1[1]; v1.z = ha1[2]; v1.w = ha1[3];
            h_acc4[(size_t)n * 8 + g]     = v0;
            h_acc4[(size_t)n * 8 + 4 + g] = v1;
            if (g == 0) {
                float4 xv; xv.x = xa0; xv.y = xa1; xv.z = xa2; xv.w = (float)deg;
                xd4[n] = xv;
            }
        }
    }
}

// ---------------- overflow registration pass (2nd look at dropped edges) ----------------
// After record_rank, cnt[d] holds the TRUE degree. Edges with rank >= MAXDEG were
// dropped; re-identify them deterministically: re-run the same atomic sequence is
// impossible, so instead record_rank handles registration inline. To keep the hot
// kernel simple we instead detect overflow nodes here and list ALL their edges'
// missing contributions via a second scan of dst (rare path, usually zero work).
__global__ __launch_bounds__(256) void ovf_scan_kernel(
    const int* __restrict__ dst, const int* __restrict__ cnt,
    int* __restrict__ ovf_cnt, int* __restrict__ ovf, int E)
{
    int e = blockIdx.x * 256 + threadIdx.x;
    int stride = gridDim.x * 256;
    for (; e < E; e += stride) {
        if (cnt[dst[e]] > MAXDEG) {
            int o = atomicAdd(ovf_cnt, 1);
            if (o < OVF_CAP) ovf[o] = e;
        }
    }
}

// fix-up: recompute overflow-node aggregates exactly, scalar path.
// For each overflow node (found via its listed edges), one thread re-aggregates
// nothing here; instead each listed edge's dst node is recomputed wholesale by
// zeroing is complex -- simpler: mark and recompute per-node using original data.
__global__ __launch_bounds__(64) void ovf_fix_kernel(
    const float* __restrict__ node_feat,
    const float* __restrict__ coord,
    const float* __restrict__ edge_feat,
    const int* __restrict__ src,
    const int* __restrict__ dst,
    const int* __restrict__ ovf_cnt,
    const int* __restrict__ ovf,
    const float* __restrict__ We1,
    const float* __restrict__ be1,
    const float* __restrict__ We2,
    const float* __restrict__ be2,
    const float* __restrict__ Wc1,
    const float* __restrict__ bc1,
    const float* __restrict__ Wc2,
    float* __restrict__ h_acc,
    float4* __restrict__ xd4,
    int E)
{
    int total = *ovf_cnt;
    if (total > OVF_CAP) total = OVF_CAP;
    for (int i = blockIdx.x * 64 + threadIdx.x; i < total; i += gridDim.x * 64) {
        int e = ovf[i];
        int s = src[e], d = dst[e];
        // only edges whose rank was >= MAXDEG were dropped; ovf_scan lists ALL edges
        // of overflowing nodes. Recompute rank order is impossible; instead the
        // fused kernel already summed the first MAXDEG records, and dropped edges
        // are exactly (deg - MAXDEG) per node but unidentifiable individually.
        // Resolution: ovf_scan lists all edges of the node; we recompute the FULL
        // sums here and overwrite. Use one thread per listed edge to atomically
        // add only if this edge was NOT among the stored records. Since stored
        // records hold src ids per slot, check membership by scanning the node's
        // 64 slots for this edge's packed signature is ambiguous. Fallback:
        // contributions of dropped edges cannot be isolated -> recompute node from
        // scratch: thread with lowest i per node zeroes and re-adds all edges.
        // Given P(overflow)~1e-8 this path is effectively dead; correctness guard:
        // recompute full aggregate for node d serially if this is the first listed
        // edge of d (detected via matching e == first occurrence).
        bool first = true;
        for (int j = 0; j < i; ++j) if (dst[ovf[j]] == d) { first = false; break; }
        if (!first) continue;
        // serial full recompute for node d
        float hsum[THID];
        #pragma unroll
        for (int j = 0; j < THID; ++j) hsum[j] = 0.f;
        float xs0 = 0.f, xs1 = 0.f, xs2 = 0.f;
        int degc = 0;
        for (int ee = 0; ee < E; ++ee) {
            if (dst[ee] != d) continue;
            ++degc;
            int ss = src[ee];
            float dx0 = coord[3*(size_t)ss+0] - coord[3*(size_t)d+0];
            float dx1 = coord[3*(size_t)ss+1] - coord[3*(size_t)d+1];
            float dx2 = coord[3*(size_t)ss+2] - coord[3*(size_t)d+2];
            float radial = dx0*dx0 + dx1*dx1 + dx2*dx2;
            float invn = 1.0f / (sqrtf(radial) + 1e-30f);
            dx0 *= invn; dx1 *= invn; dx2 *= invn;
            float f[73];
            for (int k = 0; k < 32; ++k) f[k] = node_feat[(size_t)ss*TIN + k];
            for (int k = 0; k < 32; ++k) f[32+k] = node_feat[(size_t)d*TIN + k];
            f[64] = radial;
            for (int k = 0; k < 8; ++k) f[65+k] = edge_feat[(size_t)ee*TEDGE + k];
            float a1[THID];
            for (int j = 0; j < THID; ++j) a1[j] = be1[j];
            for (int k = 0; k < 73; ++k) {
                float fk = f[k];
                for (int j = 0; j < THID; ++j) a1[j] = fmaf(fk, We1[k*THID + j], a1[j]);
            }
            for (int j = 0; j < THID; ++j) a1[j] = silu_f(a1[j]);
            float msg[THID];
            for (int j = 0; j < THID; ++j) msg[j] = be2[j];
            for (int k = 0; k < THID; ++k) {
                float fk = a1[k];
                for (int j = 0; j < THID; ++j) msg[j] = fmaf(fk, We2[k*THID + j], msg[j]);
            }
            for (int j = 0; j < THID; ++j) msg[j] = silu_f(msg[j]);
            float c1[THID];
            for (int j = 0; j < THID; ++j) c1[j] = bc1[j];
            for (int k = 0; k < THID; ++k) {
                float fk = msg[k];
                for (int j = 0; j < THID; ++j) c1[j] = fmaf(fk, Wc1[k*THID + j], c1[j]);
            }
            float gate = 0.0f;
            for (int j = 0; j < THID; ++j) gate = fmaf(silu_f(c1[j]), Wc2[j], gate);
            for (int j = 0; j < THID; ++j) hsum[j] += msg[j];
            xs0 += gate * dx0; xs1 += gate * dx1; xs2 += gate * dx2;
        }
        for (int j = 0; j < THID; ++j) h_acc[(size_t)d * THID + j] = hsum[j];
        float4 xv; xv.x = xs0; xv.y = xs1; xv.z = xs2; xv.w = (float)degc;
        xd4[d] = xv;
    }
}

// ---------------- fallback: atomic edge kernel (small-ws path) ----------------
__global__ __launch_bounds__(256) void egnn_edge_atomic(
    const float* __restrict__ node_feat,
    const float* __restrict__ coord,
    const float* __restrict__ edge_feat,
    const int*   __restrict__ src,
    const int*   __restrict__ dst,
    const float* __restrict__ We1,
    const float* __restrict__ be1,
    const float* __restrict__ We2,
    const float* __restrict__ be2,
    const float* __restrict__ Wc1,
    const float* __restrict__ bc1,
    const float* __restrict__ Wc2,
    float* __restrict__ h_acc,
    float* __restrict__ x_acc,   // [N][4] {x,y,z,deg}
    int E)
{
    int e = blockIdx.x * 256 + threadIdx.x;
    if (e >= E) return;
    int s = src[e];
    int d = dst[e];
    float dx0 = coord[3*(size_t)s+0] - coord[3*(size_t)d+0];
    float dx1 = coord[3*(size_t)s+1] - coord[3*(size_t)d+1];
    float dx2 = coord[3*(size_t)s+2] - coord[3*(size_t)d+2];
    float radial = dx0*dx0 + dx1*dx1 + dx2*dx2;
    float invn = 1.0f / (sqrtf(radial) + 1e-30f);
    dx0 *= invn; dx1 *= invn; dx2 *= invn;
    float f[73];
    #pragma unroll
    for (int i = 0; i < 32; ++i) f[i] = node_feat[(size_t)s*TIN + i];
    #pragma unroll
    for (int i = 0; i < 32; ++i) f[32+i] = node_feat[(size_t)d*TIN + i];
    f[64] = radial;
    #pragma unroll
    for (int i = 0; i < 8; ++i) f[65+i] = edge_feat[(size_t)e*TEDGE + i];
    float a1[THID];
    #pragma unroll
    for (int j = 0; j < THID; ++j) a1[j] = be1[j];
    for (int k = 0; k < 73; ++k) {
        float fk = f[k];
        #pragma unroll
        for (int j = 0; j < THID; ++j) a1[j] = fmaf(fk, We1[k*THID + j], a1[j]);
    }
    #pragma unroll
    for (int j = 0; j < THID; ++j) a1[j] = silu_f(a1[j]);
    float msg[THID];
    #pragma unroll
    for (int j = 0; j < THID; ++j) msg[j] = be2[j];
    for (int k = 0; k < THID; ++k) {
        float fk = a1[k];
        #pragma unroll
        for (int j = 0; j < THID; ++j) msg[j] = fmaf(fk, We2[k*THID + j], msg[j]);
    }
    #pragma unroll
    for (int j = 0; j < THID; ++j) msg[j] = silu_f(msg[j]);
    float c1[THID];
    #pragma unroll
    for (int j = 0; j < THID; ++j) c1[j] = bc1[j];
    for (int k = 0; k < THID; ++k) {
        float fk = msg[k];
        #pragma unroll
        for (int j = 0; j < THID; ++j) c1[j] = fmaf(fk, Wc1[k*THID + j], c1[j]);
    }
    float gate = 0.0f;
    #pragma unroll
    for (int j = 0; j < THID; ++j) gate = fmaf(silu_f(c1[j]), Wc2[j], gate);
    float* ha = h_acc + (size_t)d * THID;
    #pragma unroll
    for (int j = 0; j < THID; ++j) atomicAdd(ha + j, msg[j]);
    atomicAdd(x_acc + (size_t)d*4 + 0, gate * dx0);
    atomicAdd(x_acc + (size_t)d*4 + 1, gate * dx1);
    atomicAdd(x_acc + (size_t)d*4 + 2, gate * dx2);
    atomicAdd(x_acc + (size_t)d*4 + 3, 1.0f);
}

// ---------------- phase 3: node update ----------------
__global__ __launch_bounds__(256) void egnn_node(
    const float* __restrict__ node_feat,
    const float* __restrict__ coord,
    const float* __restrict__ Wn1,
    const float* __restrict__ bn1,
    const float* __restrict__ Wn2,
    const float* __restrict__ bn2,
    const float* __restrict__ h_acc,
    const float4* __restrict__ xd4,   // {x,y,z,deg}
    float* __restrict__ out_h,
    float* __restrict__ out_x,
    int N)
{
    int n = blockIdx.x * 256 + threadIdx.x;
    if (n >= N) return;

    float f2[2*TIN];
    {
        const float4* p = reinterpret_cast<const float4*>(node_feat + (size_t)n * TIN);
        #pragma unroll
        for (int i = 0; i < TIN/4; ++i) {
            float4 v = p[i];
            f2[4*i+0]=v.x; f2[4*i+1]=v.y; f2[4*i+2]=v.z; f2[4*i+3]=v.w;
        }
    }
    {
        const float4* p = reinterpret_cast<const float4*>(h_acc + (size_t)n * THID);
        #pragma unroll
        for (int i = 0; i < THID/4; ++i) {
            float4 v = p[i];
            f2[TIN+4*i+0]=v.x; f2[TIN+4*i+1]=v.y; f2[TIN+4*i+2]=v.z; f2[TIN+4*i+3]=v.w;
        }
    }

    float a[THID];
    #pragma unroll
    for (int j = 0; j < THID; ++j) a[j] = bn1[j];
    #pragma unroll
    for (int k = 0; k < 2*TIN; ++k) {
        float fk = f2[k];
        #pragma unroll
        for (int j = 0; j < THID; ++j) a[j] = fmaf(fk, Wn1[k*THID + j], a[j]);
    }
    #pragma unroll
    for (int j = 0; j < THID; ++j) a[j] = silu_f(a[j]);

    float h[TOUT];
    #pragma unroll
    for (int j = 0; j < TOUT; ++j) h[j] = bn2[j];
    #pragma unroll
    for (int k = 0; k < THID; ++k) {
        float fk = a[k];
        #pragma unroll
        for (int j = 0; j < TOUT; ++j) h[j] = fmaf(fk, Wn2[k*TOUT + j], h[j]);
    }

    float4* po = reinterpret_cast<float4*>(out_h + (size_t)n * TOUT);
    #pragma unroll
    for (int i = 0; i < TOUT/4; ++i) {
        float4 v; v.x=h[4*i+0]; v.y=h[4*i+1]; v.z=h[4*i+2]; v.w=h[4*i+3];
        po[i] = v;
    }

    float4 xv = xd4[n];
    float dg = fmaxf(xv.w, 1.0f);
    float inv = __builtin_amdgcn_rcpf(dg);
    out_x[(size_t)n*3+0] = coord[(size_t)n*3+0] + xv.x * inv;
    out_x[(size_t)n*3+1] = coord[(size_t)n*3+1] + xv.y * inv;
    out_x[(size_t)n*3+2] = coord[(size_t)n*3+2] + xv.z * inv;
}

extern "C" void kernel_launch(void* const* d_in, const int* in_sizes, int n_in,
                              void* d_out, int out_size, void* d_ws, size_t ws_size,
                              hipStream_t stream) {
    const float* node_feat = (const float*)d_in[0];
    const float* coord     = (const float*)d_in[1];
    const float* edge_feat = (const float*)d_in[2];
    const int*   src       = (const int*)d_in[3];
    const int*   dst       = (const int*)d_in[4];
    const float* We1 = (const float*)d_in[5];
    const float* be1 = (const float*)d_in[6];
    const float* We2 = (const float*)d_in[7];
    const float* be2 = (const float*)d_in[8];
    const float* Wn1 = (const float*)d_in[9];
    const float* bn1 = (const float*)d_in[10];
    const float* Wn2 = (const float*)d_in[11];
    const float* bn2 = (const float*)d_in[12];
    const float* Wc1 = (const float*)d_in[13];
    const float* bc1 = (const float*)d_in[14];
    const float* Wc2 = (const float*)d_in[15];

    int N = in_sizes[0] / TIN;
    int E = in_sizes[3];

    float* out_h = (float*)d_out;
    float* out_x = out_h + (size_t)N * TOUT;

    // workspace layout
    uint4*        recs    = (uint4*)d_ws;                              // N*MAXDEG*2 uint4 (32B/slot)
    unsigned int* node_bf = (unsigned int*)(recs + ((size_t)N << 6) * 2);
    float4*       coord4  = (float4*)(node_bf + (size_t)N * 16);
    float*        h_acc   = (float*)(coord4 + N);                      // N*32 f32
    float4*       xd4     = (float4*)(h_acc + (size_t)N * THID);       // N
    int*          cnt     = (int*)(xd4 + N);                           // N+1 (last = ovf counter)
    int*          ovf     = cnt + (N + 1);                             // OVF_CAP
    size_t need = (size_t)((char*)(ovf + OVF_CAP) - (char*)d_ws);

    if (need <= ws_size) {
        conv_node_kernel<<<2048, 256, 0, stream>>>(node_feat, node_bf, N * 16);
        conv_coord_kernel<<<(N + 255) / 256, 256, 0, stream>>>(coord, coord4, N);
        hipMemsetAsync(cnt, 0, (size_t)(N + 1) * 4, stream);
        record_rank_kernel<<<(E + 255) / 256, 256, 0, stream>>>(
            src, dst, coord4, edge_feat, cnt, ovf, recs, E);
        int nchunks = (N + CHUNK - 1) / CHUNK;
        egnn_fused<<<(nchunks + 3) / 4, 256, 0, stream>>>(
            (const uint4*)node_bf, recs, cnt,
            We1, be1, We2, be2, Wc1, bc1, Wc2,
            (float4*)h_acc, xd4, N);
        // overflow guard (normally zero-work): find edges of nodes with deg>MAXDEG
        ovf_scan_kernel<<<256, 256, 0, stream>>>(dst, cnt, cnt + N, ovf, E);
        ovf_fix_kernel<<<8, 64, 0, stream>>>(
            node_feat, coord, edge_feat, src, dst, cnt + N, ovf,
            We1, be1, We2, be2, Wc1, bc1, Wc2, h_acc, xd4, E);
        egnn_node<<<(N + 255) / 256, 256, 0, stream>>>(
            node_feat, coord, Wn1, bn1, Wn2, bn2,
            h_acc, xd4, out_h, out_x, N);
    } else {
        float* fh_acc = (float*)d_ws;
        float* fx_acc = fh_acc + (size_t)N * THID;   // [N][4]
        hipMemsetAsync(d_ws, 0, sizeof(float) * (size_t)N * (THID + 4), stream);
        egnn_edge_atomic<<<(E + 255) / 256, 256, 0, stream>>>(
            node_feat, coord, edge_feat, src, dst,
            We1, be1, We2, be2, Wc1, bc1, Wc2,
            fh_acc, fx_acc, E);
        egnn_node<<<(N + 255) / 256, 256, 0, stream>>>(
            node_feat, coord, Wn1, bn1, Wn2, bn2,
            fh_acc, (const float4*)fx_acc, out_h, out_x, N);
    }
}